// Round 2
// baseline (2464.800 us; speedup 1.0000x reference)
//
#include <hip/hip_runtime.h>
#include <hip/hip_bf16.h>

#define L_ 8
#define H_ 16
#define C_ 1024
#define B_ 2
#define T_ 1024
#define M_ (B_*T_)   // 2048 rows
#define DH 64
#define FF (4*C_)    // 4096

typedef __hip_bfloat16 bf16;
typedef __attribute__((ext_vector_type(8))) short s16x8;
typedef __attribute__((ext_vector_type(4))) float f32x4;

enum { EPI_BIAS = 0, EPI_VT = 1, EPI_SCORES = 2, EPI_PV = 3, EPI_RESID = 4, EPI_GELU = 5 };

__device__ __forceinline__ void stv(float* p, float v) { *p = v; }
__device__ __forceinline__ void stv(bf16* p, float v) { *p = __float2bfloat16(v); }

// ---------------- LayerNorm (one block per row, C=1024, 256 threads) ----------------
template<typename OutT>
__global__ __launch_bounds__(256) void ln_kernel(const float* __restrict__ x,
                                                 const float* __restrict__ w,
                                                 const float* __restrict__ b,
                                                 OutT* __restrict__ out) {
    int row = blockIdx.x;
    const float* xr = x + (size_t)row * C_;
    int t = threadIdx.x;
    float4 v = *(const float4*)(xr + t * 4);

    float s = v.x + v.y + v.z + v.w;
#pragma unroll
    for (int o = 32; o >= 1; o >>= 1) s += __shfl_xor(s, o);
    __shared__ float red[4];
    int wid = t >> 6, lane = t & 63;
    if (lane == 0) red[wid] = s;
    __syncthreads();
    float mean = (red[0] + red[1] + red[2] + red[3]) * (1.0f / C_);
    __syncthreads();

    float dx = v.x - mean, dy = v.y - mean, dz = v.z - mean, dw = v.w - mean;
    float ss = dx * dx + dy * dy + dz * dz + dw * dw;
#pragma unroll
    for (int o = 32; o >= 1; o >>= 1) ss += __shfl_xor(ss, o);
    if (lane == 0) red[wid] = ss;
    __syncthreads();
    float var = (red[0] + red[1] + red[2] + red[3]) * (1.0f / C_);
    float rs = rsqrtf(var + 1e-5f);

    float4 wv = *(const float4*)(w + t * 4);
    float4 bv = *(const float4*)(b + t * 4);
    OutT* orow = out + (size_t)row * C_;
    stv(orow + t * 4 + 0, dx * rs * wv.x + bv.x);
    stv(orow + t * 4 + 1, dy * rs * wv.y + bv.y);
    stv(orow + t * 4 + 2, dz * rs * wv.z + bv.z);
    stv(orow + t * 4 + 3, dw * rs * wv.w + bv.w);
}

// ---------------- fp32 [Kd][Nd] -> bf16 [Nd][Kd] transpose+convert ----------------
__global__ __launch_bounds__(256) void transpose_k(const float* __restrict__ W,
                                                   bf16* __restrict__ Wt, int Kd, int Nd) {
    __shared__ float tile[32][33];
    int tx = threadIdx.x, ty = threadIdx.y;          // (32, 8)
    int gx = blockIdx.x * 32, gy = blockIdx.y * 32;  // gx over Nd, gy over Kd
#pragma unroll
    for (int i = 0; i < 32; i += 8)
        tile[ty + i][tx] = W[(size_t)(gy + ty + i) * Nd + gx + tx];
    __syncthreads();
#pragma unroll
    for (int i = 0; i < 32; i += 8)
        Wt[(size_t)(gx + ty + i) * Kd + gy + tx] = __float2bfloat16(tile[tx][ty + i]);
}

// ---------------- MFMA GEMM tile: C[M,N] = A[M,K](bf16,row) @ Bt[N,K](bf16,row)^T ----------------
// 256 threads, 2x2 waves, wave tile (BM/2)x(BN/2), 16x16x32 bf16 MFMA, BK=32 single-buffered.
template<int BM, int BN, int EPI>
__device__ __forceinline__ void gemm_tile(const bf16* __restrict__ A, int lda,
                                          const bf16* __restrict__ Bt, int ldb,
                                          const float* __restrict__ bias,
                                          void* __restrict__ Cout, int ldc,
                                          int K, int bm0, int bn0, float scale) {
    constexpr int WM = BM / 2, WN = BN / 2, MR = WM / 16, NR = WN / 16;
    constexpr int LDSTR = 40;  // +8 bf16 pad: 80B row stride, 16B-aligned, ~2-way banks
    __shared__ short lds[(BM + BN) * LDSTR];
    short* As = lds;
    short* Bs = lds + BM * LDSTR;

    int tid = threadIdx.x;
    int wid = tid >> 6, lane = tid & 63;
    int wr = wid >> 1, wc = wid & 1;
    int lr = lane & 15, lg = lane >> 4;

    f32x4 acc[MR][NR];
    const f32x4 z4 = {0.f, 0.f, 0.f, 0.f};
#pragma unroll
    for (int m = 0; m < MR; ++m)
#pragma unroll
        for (int n = 0; n < NR; ++n) acc[m][n] = z4;

    const short* Ap = (const short*)A;
    const short* Bp = (const short*)Bt;

    for (int k0 = 0; k0 < K; k0 += 32) {
        __syncthreads();
#pragma unroll
        for (int ci = 0; ci < BM / 64; ++ci) {
            int lin = (ci * 256 + tid) * 8;
            int r = lin >> 5, c = lin & 31;
            s16x8 va = *(const s16x8*)(Ap + (size_t)(bm0 + r) * lda + (k0 + c));
            *(s16x8*)&As[r * LDSTR + c] = va;
        }
#pragma unroll
        for (int ci = 0; ci < BN / 64; ++ci) {
            int lin = (ci * 256 + tid) * 8;
            int r = lin >> 5, c = lin & 31;
            s16x8 vb = *(const s16x8*)(Bp + (size_t)(bn0 + r) * ldb + (k0 + c));
            *(s16x8*)&Bs[r * LDSTR + c] = vb;
        }
        __syncthreads();

        s16x8 af[MR], bfr[NR];
#pragma unroll
        for (int m = 0; m < MR; ++m)
            af[m] = *(const s16x8*)&As[(wr * WM + m * 16 + lr) * LDSTR + lg * 8];
#pragma unroll
        for (int n = 0; n < NR; ++n)
            bfr[n] = *(const s16x8*)&Bs[(wc * WN + n * 16 + lr) * LDSTR + lg * 8];
#pragma unroll
        for (int m = 0; m < MR; ++m)
#pragma unroll
            for (int n = 0; n < NR; ++n)
                acc[m][n] = __builtin_amdgcn_mfma_f32_16x16x32_bf16(af[m], bfr[n], acc[m][n], 0, 0, 0);
    }

    // epilogue: C/D layout col=lane&15, row=(lane>>4)*4+i   [verified m89]
#pragma unroll
    for (int m = 0; m < MR; ++m)
#pragma unroll
        for (int n = 0; n < NR; ++n)
#pragma unroll
            for (int i = 0; i < 4; ++i) {
                int gm = bm0 + wr * WM + m * 16 + lg * 4 + i;
                int gn = bn0 + wc * WN + n * 16 + lr;
                float vacc = acc[m][n][i];
                if constexpr (EPI == EPI_BIAS) {
                    ((bf16*)Cout)[(size_t)gm * ldc + gn] = __float2bfloat16(vacc + bias[gn]);
                } else if constexpr (EPI == EPI_VT) {
                    // gm=b*T+t, gn=h*64+d  ->  vT[((b*H+h)*64+d)*T + t] ; (b*H+h)*64+d == b*1024+gn
                    int bb = gm >> 10, tt = gm & 1023;
                    ((bf16*)Cout)[((size_t)(bb * 1024 + gn)) * T_ + tt] =
                        __float2bfloat16(vacc + bias[gn]);
                } else if constexpr (EPI == EPI_SCORES) {
                    float vv = vacc * scale;
                    if (gn > gm) vv = -1e30f;  // causal mask
                    ((float*)Cout)[(size_t)gm * ldc + gn] = vv;
                } else if constexpr (EPI == EPI_PV) {
                    ((bf16*)Cout)[(size_t)gm * ldc + gn] = __float2bfloat16(vacc);
                } else if constexpr (EPI == EPI_RESID) {
                    float* cp = (float*)Cout + (size_t)gm * ldc + gn;
                    *cp = *cp + vacc + bias[gn];
                } else if constexpr (EPI == EPI_GELU) {
                    float xg = vacc + bias[gn];
                    float g = 0.5f * xg * (1.0f + erff(xg * 0.70710678118654752f));
                    ((bf16*)Cout)[(size_t)gm * ldc + gn] = __float2bfloat16(g);
                }
            }
}

template<int BM, int BN, int EPI>
__global__ __launch_bounds__(256) void gemm_std(const bf16* A, int lda, const bf16* Bt, int ldb,
                                                const float* bias, void* Cout, int ldc, int K) {
    gemm_tile<BM, BN, EPI>(A, lda, Bt, ldb, bias, Cout, ldc, K,
                           blockIdx.y * BM, blockIdx.x * BN, 0.f);
}

__global__ __launch_bounds__(256) void gemm_scores_k(const bf16* q, const bf16* k, float* S, int c0) {
    int p = c0 + blockIdx.z;
    int bb = p >> 4, hh = p & 15;
    const bf16* A = q + ((size_t)bb * T_) * C_ + hh * DH;
    const bf16* Bt = k + ((size_t)bb * T_) * C_ + hh * DH;
    float* Cz = S + (size_t)blockIdx.z * T_ * T_;
    gemm_tile<128, 128, EPI_SCORES>(A, C_, Bt, C_, nullptr, Cz, T_, DH,
                                    blockIdx.y * 128, blockIdx.x * 128, 0.125f);
}

__global__ __launch_bounds__(256) void gemm_pv_k(const bf16* P, const bf16* vT, bf16* y, int c0) {
    int p = c0 + blockIdx.z;
    int bb = p >> 4, hh = p & 15;
    const bf16* A = P + (size_t)blockIdx.z * T_ * T_;
    const bf16* Bt = vT + (size_t)p * DH * T_;
    bf16* Cz = y + ((size_t)bb * T_) * C_ + hh * DH;
    gemm_tile<64, 64, EPI_PV>(A, T_, Bt, T_, nullptr, Cz, C_, T_,
                              blockIdx.y * 64, blockIdx.x * 64, 0.f);
}

// ---------------- row softmax: fp32 scores row -> bf16 probs row ----------------
__global__ __launch_bounds__(256) void softmax_k(const float* __restrict__ S, bf16* __restrict__ P) {
    size_t row = blockIdx.x;
    const float* sr = S + row * T_;
    bf16* pr = P + row * T_;
    int t = threadIdx.x;
    float4 v = *(const float4*)(sr + t * 4);

    float mx = fmaxf(fmaxf(v.x, v.y), fmaxf(v.z, v.w));
#pragma unroll
    for (int o = 32; o >= 1; o >>= 1) mx = fmaxf(mx, __shfl_xor(mx, o));
    __shared__ float red[4];
    int wid = t >> 6, lane = t & 63;
    if (lane == 0) red[wid] = mx;
    __syncthreads();
    mx = fmaxf(fmaxf(red[0], red[1]), fmaxf(red[2], red[3]));
    __syncthreads();

    float e0 = __expf(v.x - mx), e1 = __expf(v.y - mx);
    float e2 = __expf(v.z - mx), e3 = __expf(v.w - mx);
    float s = e0 + e1 + e2 + e3;
#pragma unroll
    for (int o = 32; o >= 1; o >>= 1) s += __shfl_xor(s, o);
    if (lane == 0) red[wid] = s;
    __syncthreads();
    float inv = 1.0f / (red[0] + red[1] + red[2] + red[3]);
    pr[t * 4 + 0] = __float2bfloat16(e0 * inv);
    pr[t * 4 + 1] = __float2bfloat16(e1 * inv);
    pr[t * 4 + 2] = __float2bfloat16(e2 * inv);
    pr[t * 4 + 3] = __float2bfloat16(e3 * inv);
}

extern "C" void kernel_launch(void* const* d_in, const int* in_sizes, int n_in,
                              void* d_out, int out_size, void* d_ws, size_t ws_size,
                              hipStream_t stream) {
    const float* x     = (const float*)d_in[0];
    const float* Wq    = (const float*)d_in[1];
    const float* Wk    = (const float*)d_in[2];
    const float* Wv    = (const float*)d_in[3];
    const float* Wp    = (const float*)d_in[4];
    const float* bq    = (const float*)d_in[5];
    const float* bk    = (const float*)d_in[6];
    const float* bv    = (const float*)d_in[7];
    const float* bp    = (const float*)d_in[8];
    const float* ln1w  = (const float*)d_in[9];
    const float* ln1b  = (const float*)d_in[10];
    const float* ln2w  = (const float*)d_in[11];
    const float* ln2b  = (const float*)d_in[12];
    const float* W1    = (const float*)d_in[13];
    const float* b1    = (const float*)d_in[14];
    const float* W2    = (const float*)d_in[15];
    const float* b2    = (const float*)d_in[16];
    const float* lnfw  = (const float*)d_in[17];
    const float* lnfb  = (const float*)d_in[18];

    float* h = (float*)d_out;  // residual stream lives in d_out (fp32 [M,C])
    hipMemcpyAsync(h, x, (size_t)M_ * C_ * 4, hipMemcpyDeviceToDevice, stream);

    // ---- workspace carve ----
    char* base = (char*)d_ws;
    size_t off = 0;
    auto carve = [&](size_t bytes) {
        char* r = base + off;
        off += (bytes + 255) & ~(size_t)255;
        return r;
    };
    bf16* a   = (bf16*)carve((size_t)M_ * C_ * 2);
    bf16* qb  = (bf16*)carve((size_t)M_ * C_ * 2);
    bf16* kb  = (bf16*)carve((size_t)M_ * C_ * 2);
    bf16* vT  = (bf16*)carve((size_t)M_ * C_ * 2);   // [B*H, 64, T]
    bf16* yb  = (bf16*)carve((size_t)M_ * C_ * 2);
    bf16* hid = (bf16*)carve((size_t)M_ * FF * 2);
    bf16* wt  = (bf16*)carve((size_t)C_ * FF * 2);   // transposed-weight staging (max 8MB)

    const int NP = B_ * H_;  // 32 (b,h) pairs
    int CH = 32;             // attention chunk: S fp32 CH*4MB + P bf16 CH*2MB
    while (CH > 1 && off + (size_t)CH * T_ * T_ * 6 + 1024 > ws_size) CH >>= 1;
    float* S = (float*)carve((size_t)CH * T_ * T_ * 4);
    bf16*  P = (bf16*)carve((size_t)CH * T_ * T_ * 2);

    dim3 tb(256);
    dim3 tpb(32, 8);
    dim3 gCC(C_ / 32, C_ / 32);

    for (int l = 0; l < L_; ++l) {
        // LN1 -> a (bf16)
        ln_kernel<bf16><<<M_, tb, 0, stream>>>(h, ln1w + l * C_, ln1b + l * C_, a);

        // Q
        transpose_k<<<gCC, tpb, 0, stream>>>(Wq + (size_t)l * C_ * C_, wt, C_, C_);
        gemm_std<64, 128, EPI_BIAS><<<dim3(8, 32), tb, 0, stream>>>(a, C_, wt, C_, bq + l * C_, qb, C_, C_);
        // K
        transpose_k<<<gCC, tpb, 0, stream>>>(Wk + (size_t)l * C_ * C_, wt, C_, C_);
        gemm_std<64, 128, EPI_BIAS><<<dim3(8, 32), tb, 0, stream>>>(a, C_, wt, C_, bk + l * C_, kb, C_, C_);
        // V (written transposed per head: vT[(b*H+h)*64+d][t])
        transpose_k<<<gCC, tpb, 0, stream>>>(Wv + (size_t)l * C_ * C_, wt, C_, C_);
        gemm_std<64, 128, EPI_VT><<<dim3(8, 32), tb, 0, stream>>>(a, C_, wt, C_, bv + l * C_, vT, T_, C_);

        // attention, chunked over (b,h) pairs
        for (int c0 = 0; c0 < NP; c0 += CH) {
            gemm_scores_k<<<dim3(8, 8, CH), tb, 0, stream>>>(qb, kb, S, c0);
            softmax_k<<<CH * T_, tb, 0, stream>>>(S, P);
            gemm_pv_k<<<dim3(1, 16, CH), tb, 0, stream>>>(P, vT, yb, c0);
        }

        // out proj + residual into h
        transpose_k<<<gCC, tpb, 0, stream>>>(Wp + (size_t)l * C_ * C_, wt, C_, C_);
        gemm_std<64, 128, EPI_RESID><<<dim3(8, 32), tb, 0, stream>>>(yb, C_, wt, C_, bp + l * C_, h, C_, C_);

        // LN2 -> a
        ln_kernel<bf16><<<M_, tb, 0, stream>>>(h, ln2w + l * C_, ln2b + l * C_, a);

        // MLP up + GELU -> hid (bf16)
        transpose_k<<<dim3(FF / 32, C_ / 32), tpb, 0, stream>>>(W1 + (size_t)l * C_ * FF, wt, C_, FF);
        gemm_std<128, 128, EPI_GELU><<<dim3(FF / 128, M_ / 128), tb, 0, stream>>>(a, C_, wt, C_, b1 + l * FF, hid, FF, C_);

        // MLP down + residual into h
        transpose_k<<<dim3(C_ / 32, FF / 32), tpb, 0, stream>>>(W2 + (size_t)l * FF * C_, wt, FF, C_);
        gemm_std<64, 128, EPI_RESID><<<dim3(8, 32), tb, 0, stream>>>(hid, FF, wt, FF, b2 + l * C_, h, C_, FF);
    }

    // final LN in place (fp32 out)
    ln_kernel<float><<<M_, tb, 0, stream>>>(h, lnfw, lnfb, h);
}

// Round 3
// 2008.684 us; speedup vs baseline: 1.2271x; 1.2271x over previous
//
#include <hip/hip_runtime.h>
#include <hip/hip_bf16.h>

#define L_ 8
#define H_ 16
#define C_ 1024
#define B_ 2
#define T_ 1024
#define M_ (B_*T_)   // 2048 rows
#define DH 64
#define FF (4*C_)    // 4096

typedef __hip_bfloat16 bf16;
typedef __attribute__((ext_vector_type(8))) short s16x8;
typedef __attribute__((ext_vector_type(4))) float f32x4;

enum { EPI_QKV = 0, EPI_SCORES = 1, EPI_PV = 2, EPI_RESID = 3, EPI_GELU = 4, EPI_PARTIAL = 5 };

__device__ __forceinline__ void gload16(const void* g, void* l) {
    __builtin_amdgcn_global_load_lds(
        (const __attribute__((address_space(1))) unsigned int*)g,
        (__attribute__((address_space(3))) unsigned int*)l, 16, 0, 0);
}

// ---------------- LayerNorm (one block per row, C=1024, 256 threads) ----------------
__device__ __forceinline__ void stv(float* p, float v) { *p = v; }
__device__ __forceinline__ void stv(bf16* p, float v) { *p = __float2bfloat16(v); }

template<typename OutT>
__global__ __launch_bounds__(256) void ln_kernel(const float* __restrict__ x,
                                                 const float* __restrict__ w,
                                                 const float* __restrict__ b,
                                                 OutT* __restrict__ out) {
    int row = blockIdx.x;
    const float* xr = x + (size_t)row * C_;
    int t = threadIdx.x;
    float4 v = *(const float4*)(xr + t * 4);

    float s = v.x + v.y + v.z + v.w;
#pragma unroll
    for (int o = 32; o >= 1; o >>= 1) s += __shfl_xor(s, o);
    __shared__ float red[4];
    int wid = t >> 6, lane = t & 63;
    if (lane == 0) red[wid] = s;
    __syncthreads();
    float mean = (red[0] + red[1] + red[2] + red[3]) * (1.0f / C_);
    __syncthreads();

    float dx = v.x - mean, dy = v.y - mean, dz = v.z - mean, dw = v.w - mean;
    float ss = dx * dx + dy * dy + dz * dz + dw * dw;
#pragma unroll
    for (int o = 32; o >= 1; o >>= 1) ss += __shfl_xor(ss, o);
    if (lane == 0) red[wid] = ss;
    __syncthreads();
    float var = (red[0] + red[1] + red[2] + red[3]) * (1.0f / C_);
    float rs = rsqrtf(var + 1e-5f);

    float4 wv = *(const float4*)(w + t * 4);
    float4 bv = *(const float4*)(b + t * 4);
    OutT* orow = out + (size_t)row * C_;
    stv(orow + t * 4 + 0, dx * rs * wv.x + bv.x);
    stv(orow + t * 4 + 1, dy * rs * wv.y + bv.y);
    stv(orow + t * 4 + 2, dz * rs * wv.z + bv.z);
    stv(orow + t * 4 + 3, dw * rs * wv.w + bv.w);
}

// ---------- fp32 [Kd][Nd] -> bf16 [Nd][Kd] transpose+convert, z batches up to 3 ----------
__global__ __launch_bounds__(256) void transpose_k(const float* __restrict__ W0,
                                                   const float* __restrict__ W1,
                                                   const float* __restrict__ W2,
                                                   bf16* __restrict__ Wt, int Kd, int Nd) {
    const float* W = (blockIdx.z == 0) ? W0 : (blockIdx.z == 1) ? W1 : W2;
    bf16* dst = Wt + (size_t)blockIdx.z * Kd * Nd;
    __shared__ float tile[32][33];
    int tx = threadIdx.x, ty = threadIdx.y;          // (32, 8)
    int gx = blockIdx.x * 32, gy = blockIdx.y * 32;  // gx over Nd, gy over Kd
#pragma unroll
    for (int i = 0; i < 32; i += 8)
        tile[ty + i][tx] = W[(size_t)(gy + ty + i) * Nd + gx + tx];
    __syncthreads();
#pragma unroll
    for (int i = 0; i < 32; i += 8)
        dst[(size_t)(gx + ty + i) * Kd + gy + tx] = __float2bfloat16(tile[tx][ty + i]);
}

// ---------------- MFMA GEMM tile, m97-class: BK=64, global_load_lds(16B), linear LDS ----------------
// 256 threads = 2x2 waves; wave tile (BM/2)x(BN/2); 16x16x32 bf16 MFMA.
template<int BM, int BN, int EPI>
__device__ __forceinline__ void gemm_tile(const bf16* __restrict__ A_, int lda,
                                          const bf16* __restrict__ Bt_, int ldb,
                                          const float* __restrict__ bias,
                                          void* __restrict__ C0, void* __restrict__ C1,
                                          void* __restrict__ C2, int ldc,
                                          int K, int bm0, int bn0, float scale) {
    constexpr int WM = BM / 2, WN = BN / 2, MR = WM / 16, NR = WN / 16;
    __shared__ __align__(16) short As[BM * 64];
    __shared__ __align__(16) short Bs[BN * 64];
    const short* Ap = (const short*)A_;
    const short* Bp = (const short*)Bt_;

    int tid = threadIdx.x;
    int wid = tid >> 6, lane = tid & 63, lr = lane & 15, lg = lane >> 4;
    int wr = wid >> 1, wc = wid & 1;

    f32x4 acc[MR][NR];
    const f32x4 z4 = {0.f, 0.f, 0.f, 0.f};
#pragma unroll
    for (int m = 0; m < MR; ++m)
#pragma unroll
        for (int n = 0; n < NR; ++n) acc[m][n] = z4;

    for (int k0 = 0; k0 < K; k0 += 64) {
        __syncthreads();  // previous iter's ds_reads done before overwrite
#pragma unroll
        for (int i = 0; i < BM / 32; ++i) {
            int e = (i * 256 + tid) * 8;  // linear bf16 index in [BM][64] tile
            gload16(Ap + (size_t)(bm0 + (e >> 6)) * lda + (k0 + (e & 63)),
                    As + (i * 256 + wid * 64) * 8);  // wave-uniform LDS base
        }
#pragma unroll
        for (int i = 0; i < BN / 32; ++i) {
            int e = (i * 256 + tid) * 8;
            gload16(Bp + (size_t)(bn0 + (e >> 6)) * ldb + (k0 + (e & 63)),
                    Bs + (i * 256 + wid * 64) * 8);
        }
        asm volatile("s_waitcnt vmcnt(0)" ::: "memory");
        __syncthreads();

        s16x8 af[MR][2], bfv[NR][2];
#pragma unroll
        for (int m = 0; m < MR; ++m)
#pragma unroll
            for (int ks = 0; ks < 2; ++ks)
                af[m][ks] = *(const s16x8*)&As[(wr * WM + m * 16 + lr) * 64 + ks * 32 + lg * 8];
#pragma unroll
        for (int n = 0; n < NR; ++n)
#pragma unroll
            for (int ks = 0; ks < 2; ++ks)
                bfv[n][ks] = *(const s16x8*)&Bs[(wc * WN + n * 16 + lr) * 64 + ks * 32 + lg * 8];
#pragma unroll
        for (int m = 0; m < MR; ++m)
#pragma unroll
            for (int n = 0; n < NR; ++n)
#pragma unroll
                for (int ks = 0; ks < 2; ++ks)
                    acc[m][n] = __builtin_amdgcn_mfma_f32_16x16x32_bf16(af[m][ks], bfv[n][ks],
                                                                        acc[m][n], 0, 0, 0);
    }

    // epilogue: C/D layout col=lane&15, row=(lane>>4)*4+i   [verified m89]
#pragma unroll
    for (int m = 0; m < MR; ++m)
#pragma unroll
        for (int n = 0; n < NR; ++n)
#pragma unroll
            for (int i = 0; i < 4; ++i) {
                int gm = bm0 + wr * WM + m * 16 + lg * 4 + i;
                int gn = bn0 + wc * WN + n * 16 + lr;
                float v = acc[m][n][i];
                if constexpr (EPI == EPI_QKV) {
                    float vb = v + bias[gn];
                    if (gn < 2048) {
                        bf16* dst = (gn < 1024) ? (bf16*)C0 : (bf16*)C1;
                        dst[(size_t)gm * C_ + (gn & 1023)] = __float2bfloat16(vb);
                    } else {
                        int d = gn - 2048, bb = gm >> 10, tt = gm & 1023;
                        ((bf16*)C2)[((size_t)(bb * 1024 + d)) * T_ + tt] = __float2bfloat16(vb);
                    }
                } else if constexpr (EPI == EPI_SCORES) {
                    float vv = v * scale;
                    if (gn > gm) vv = -1e30f;  // causal mask
                    ((float*)C0)[(size_t)gm * ldc + gn] = vv;
                } else if constexpr (EPI == EPI_PV) {
                    ((bf16*)C0)[(size_t)gm * ldc + gn] = __float2bfloat16(v);
                } else if constexpr (EPI == EPI_RESID) {
                    float* cp = (float*)C0 + (size_t)gm * ldc + gn;
                    *cp = *cp + v + bias[gn];
                } else if constexpr (EPI == EPI_GELU) {
                    float xg = v + bias[gn];
                    float g = 0.5f * xg * (1.0f + erff(xg * 0.70710678118654752f));
                    ((bf16*)C0)[(size_t)gm * ldc + gn] = __float2bfloat16(g);
                } else if constexpr (EPI == EPI_PARTIAL) {
                    ((float*)C0)[(size_t)gm * ldc + gn] = v;
                }
            }
}

// ---------------- GEMM wrappers ----------------
template<int BM, int BN, int EPI>
__global__ __launch_bounds__(256) void gemm_k(const bf16* A, int lda, const bf16* Bt, int ldb,
                                              const float* bias, void* C0, int ldc, int K) {
    gemm_tile<BM, BN, EPI>(A, lda, Bt, ldb, bias, C0, nullptr, nullptr, ldc, K,
                           blockIdx.y * BM, blockIdx.x * BN, 0.f);
}

__global__ __launch_bounds__(256) void gemm_qkv_k(const bf16* a, const bf16* wt, const float* bqkv,
                                                  bf16* qb, bf16* kb, bf16* vT) {
    gemm_tile<128, 128, EPI_QKV>(a, C_, wt, C_, bqkv, qb, kb, vT, 0, C_,
                                 blockIdx.y * 128, blockIdx.x * 128, 0.f);
}

// split-K over blockIdx.z: partial z covers k in [z*Ksl, (z+1)*Ksl), output to part + z*M*C
__global__ __launch_bounds__(256) void gemm_splitk_k(const bf16* A, int lda, const bf16* Bt, int ldb,
                                                     float* part, int Ksl) {
    int z = blockIdx.z;
    gemm_tile<128, 128, EPI_PARTIAL>(A + (size_t)z * Ksl, lda, Bt + (size_t)z * Ksl, ldb, nullptr,
                                     part + (size_t)z * M_ * C_, nullptr, nullptr, C_, Ksl,
                                     blockIdx.y * 128, blockIdx.x * 128, 0.f);
}

__global__ __launch_bounds__(256) void combine_k(float* __restrict__ h, const float* __restrict__ part,
                                                 const float* __restrict__ bias) {
    int i = blockIdx.x * 256 + threadIdx.x;  // float4 index over M*C/4
    float4 a = ((const float4*)part)[i];
    float4 b = ((const float4*)(part + (size_t)M_ * C_))[i];
    float4 hv = ((const float4*)h)[i];
    float4 bb = ((const float4*)bias)[i & (C_ / 4 - 1)];
    hv.x += a.x + b.x + bb.x; hv.y += a.y + b.y + bb.y;
    hv.z += a.z + b.z + bb.z; hv.w += a.w + b.w + bb.w;
    ((float4*)h)[i] = hv;
}

__global__ __launch_bounds__(256) void gemm_scores_k(const bf16* q, const bf16* k, float* S, int c0) {
    int bm0 = blockIdx.y * 128, bn0 = blockIdx.x * 128;
    if (bn0 >= bm0 + 128) return;  // fully-masked block: never read by softmax
    int p = c0 + blockIdx.z;
    int bb = p >> 4, hh = p & 15;
    const bf16* A = q + ((size_t)bb * T_) * C_ + hh * DH;
    const bf16* Bt = k + ((size_t)bb * T_) * C_ + hh * DH;
    float* Cz = S + (size_t)blockIdx.z * T_ * T_;
    gemm_tile<128, 128, EPI_SCORES>(A, C_, Bt, C_, nullptr, Cz, nullptr, nullptr, T_, DH,
                                    bm0, bn0, 0.125f);
}

__global__ __launch_bounds__(256) void gemm_pv_k(const bf16* P, const bf16* vT, bf16* y, int c0) {
    int z = blockIdx.z, p = c0 + z;
    int bb = p >> 4, hh = p & 15;
    int bm0 = blockIdx.y * 64;
    const bf16* A = P + (size_t)z * T_ * T_;
    const bf16* Bt = vT + (size_t)(bb * 1024 + hh * DH) * T_;
    bf16* Cz = y + ((size_t)bb * T_) * C_ + hh * DH;
    gemm_tile<64, 64, EPI_PV>(A, T_, Bt, T_, nullptr, Cz, nullptr, nullptr, C_,
                              bm0 + 64 /*Klim: P[r][k]=0 for k>r*/, bm0, 0, 0.f);
}

// ---------- triangular row softmax: fp32 scores -> bf16 probs, cols 0..(r|63) ----------
__global__ __launch_bounds__(256) void softmax_k(const float* __restrict__ S, bf16* __restrict__ P) {
    int row = blockIdx.x;
    int r = row & (T_ - 1);
    const float* sr = S + (size_t)row * T_;
    bf16* pr = P + (size_t)row * T_;
    int t = threadIdx.x, c0 = t * 4;
    int wlim = (r | 63) + 1;  // write limit — exactly what PV's Klim reads
    bool act = c0 < wlim;

    float xs[4];
    if (act) {
        float4 v = *(const float4*)(sr + c0);
        xs[0] = v.x; xs[1] = v.y; xs[2] = v.z; xs[3] = v.w;
    }
#pragma unroll
    for (int j = 0; j < 4; ++j)
        if (!act || c0 + j > r) xs[j] = -1e30f;

    float mx = fmaxf(fmaxf(xs[0], xs[1]), fmaxf(xs[2], xs[3]));
#pragma unroll
    for (int o = 32; o >= 1; o >>= 1) mx = fmaxf(mx, __shfl_xor(mx, o));
    __shared__ float red[4];
    int wid = t >> 6, lane = t & 63;
    if (lane == 0) red[wid] = mx;
    __syncthreads();
    mx = fmaxf(fmaxf(red[0], red[1]), fmaxf(red[2], red[3]));
    __syncthreads();

    float e[4], s = 0.f;
#pragma unroll
    for (int j = 0; j < 4; ++j) {
        e[j] = (c0 + j <= r) ? __expf(xs[j] - mx) : 0.f;
        s += e[j];
    }
#pragma unroll
    for (int o = 32; o >= 1; o >>= 1) s += __shfl_xor(s, o);
    if (lane == 0) red[wid] = s;
    __syncthreads();
    float inv = 1.0f / (red[0] + red[1] + red[2] + red[3]);
    if (act) {
        pr[c0 + 0] = __float2bfloat16(e[0] * inv);
        pr[c0 + 1] = __float2bfloat16(e[1] * inv);
        pr[c0 + 2] = __float2bfloat16(e[2] * inv);
        pr[c0 + 3] = __float2bfloat16(e[3] * inv);
    }
}

extern "C" void kernel_launch(void* const* d_in, const int* in_sizes, int n_in,
                              void* d_out, int out_size, void* d_ws, size_t ws_size,
                              hipStream_t stream) {
    const float* x     = (const float*)d_in[0];
    const float* Wq    = (const float*)d_in[1];
    const float* Wk    = (const float*)d_in[2];
    const float* Wv    = (const float*)d_in[3];
    const float* Wp    = (const float*)d_in[4];
    const float* bq    = (const float*)d_in[5];
    const float* bk    = (const float*)d_in[6];
    const float* bv    = (const float*)d_in[7];
    const float* bp    = (const float*)d_in[8];
    const float* ln1w  = (const float*)d_in[9];
    const float* ln1b  = (const float*)d_in[10];
    const float* ln2w  = (const float*)d_in[11];
    const float* ln2b  = (const float*)d_in[12];
    const float* W1    = (const float*)d_in[13];
    const float* b1    = (const float*)d_in[14];
    const float* W2    = (const float*)d_in[15];
    const float* b2    = (const float*)d_in[16];
    const float* lnfw  = (const float*)d_in[17];
    const float* lnfb  = (const float*)d_in[18];

    float* h = (float*)d_out;  // residual stream lives in d_out (fp32 [M,C])
    hipMemcpyAsync(h, x, (size_t)M_ * C_ * 4, hipMemcpyDeviceToDevice, stream);

    // ---- workspace carve ----
    char* base = (char*)d_ws;
    size_t off = 0;
    auto carve = [&](size_t bytes) {
        char* r = base + off;
        off += (bytes + 255) & ~(size_t)255;
        return r;
    };
    bf16*  a    = (bf16*)carve((size_t)M_ * C_ * 2);
    bf16*  qb   = (bf16*)carve((size_t)M_ * C_ * 2);
    bf16*  kb   = (bf16*)carve((size_t)M_ * C_ * 2);
    bf16*  vT   = (bf16*)carve((size_t)M_ * C_ * 2);   // [B*H*64, T]
    bf16*  yb   = (bf16*)carve((size_t)M_ * C_ * 2);
    bf16*  hid  = (bf16*)carve((size_t)M_ * FF * 2);
    bf16*  wt   = (bf16*)carve((size_t)C_ * FF * 2);   // transposed-weight staging (8MB)
    float* bqkv = (float*)carve(3 * C_ * 4);
    float* part = (float*)carve((size_t)2 * M_ * C_ * 4);  // split-K partials (16MB)

    const int NP = B_ * H_;  // 32 (b,h) pairs
    int CH = 32;
    while (CH > 1 && off + (size_t)CH * T_ * T_ * 6 + 1024 > ws_size) CH >>= 1;
    float* S = (float*)carve((size_t)CH * T_ * T_ * 4);
    bf16*  P = (bf16*)carve((size_t)CH * T_ * T_ * 2);

    dim3 tb(256);
    dim3 tpb(32, 8);

    for (int l = 0; l < L_; ++l) {
        // LN1 -> a (bf16)
        ln_kernel<bf16><<<M_, tb, 0, stream>>>(h, ln1w + l * C_, ln1b + l * C_, a);

        // QKV fused: transpose Wq|Wk|Wv -> wt [3C][C], pack biases, one N=3072 GEMM
        transpose_k<<<dim3(32, 32, 3), tpb, 0, stream>>>(Wq + (size_t)l * C_ * C_,
                                                         Wk + (size_t)l * C_ * C_,
                                                         Wv + (size_t)l * C_ * C_, wt, C_, C_);
        hipMemcpyAsync(bqkv,          bq + l * C_, C_ * 4, hipMemcpyDeviceToDevice, stream);
        hipMemcpyAsync(bqkv + C_,     bk + l * C_, C_ * 4, hipMemcpyDeviceToDevice, stream);
        hipMemcpyAsync(bqkv + 2 * C_, bv + l * C_, C_ * 4, hipMemcpyDeviceToDevice, stream);
        gemm_qkv_k<<<dim3(24, 16), tb, 0, stream>>>(a, wt, bqkv, qb, kb, vT);

        // attention, chunked over (b,h) pairs
        for (int c0 = 0; c0 < NP; c0 += CH) {
            gemm_scores_k<<<dim3(8, 8, CH), tb, 0, stream>>>(qb, kb, S, c0);
            softmax_k<<<CH * T_, tb, 0, stream>>>(S, P);
            gemm_pv_k<<<dim3(1, 16, CH), tb, 0, stream>>>(P, vT, yb, c0);
        }

        // out proj + residual into h  (64x128 tile -> 256 blocks)
        transpose_k<<<dim3(32, 32, 1), tpb, 0, stream>>>(Wp + (size_t)l * C_ * C_, nullptr, nullptr,
                                                         wt, C_, C_);
        gemm_k<64, 128, EPI_RESID><<<dim3(8, 32), tb, 0, stream>>>(yb, C_, wt, C_, bp + l * C_,
                                                                   h, C_, C_);

        // LN2 -> a
        ln_kernel<bf16><<<M_, tb, 0, stream>>>(h, ln2w + l * C_, ln2b + l * C_, a);

        // MLP up + GELU -> hid
        transpose_k<<<dim3(FF / 32, C_ / 32, 1), tpb, 0, stream>>>(W1 + (size_t)l * C_ * FF, nullptr,
                                                                   nullptr, wt, C_, FF);
        gemm_k<128, 128, EPI_GELU><<<dim3(FF / 128, M_ / 128), tb, 0, stream>>>(a, C_, wt, C_,
                                                                                b1 + l * FF, hid, FF, C_);

        // MLP down: split-K=2 into partials, then combine (+bias +residual)
        transpose_k<<<dim3(C_ / 32, FF / 32, 1), tpb, 0, stream>>>(W2 + (size_t)l * FF * C_, nullptr,
                                                                   nullptr, wt, FF, C_);
        gemm_splitk_k<<<dim3(8, 16, 2), tb, 0, stream>>>(hid, FF, wt, FF, part, FF / 2);
        combine_k<<<M_ * C_ / 1024, tb, 0, stream>>>(h, part, b2 + l * C_);
    }

    // final LN in place (fp32 out)
    ln_kernel<float><<<M_, tb, 0, stream>>>(h, lnfw, lnfb, h);
}

// Round 4
// 1722.705 us; speedup vs baseline: 1.4308x; 1.1660x over previous
//
#include <hip/hip_runtime.h>
#include <hip/hip_bf16.h>

#define L_ 8
#define H_ 16
#define C_ 1024
#define B_ 2
#define T_ 1024
#define M_ (B_*T_)   // 2048 rows
#define DH 64
#define FF (4*C_)    // 4096

typedef __hip_bfloat16 bf16;
typedef __attribute__((ext_vector_type(8))) short s16x8;
typedef __attribute__((ext_vector_type(4))) float f32x4;

enum { EPI_QKV = 0, EPI_RESID = 1, EPI_GELU = 2, EPI_PARTIAL = 3 };

__device__ __forceinline__ void gload16(const void* g, void* l) {
    __builtin_amdgcn_global_load_lds(
        (const __attribute__((address_space(1))) unsigned int*)g,
        (__attribute__((address_space(3))) unsigned int*)l, 16, 0, 0);
}

__device__ __forceinline__ unsigned packbf(float lo, float hi) {
    unsigned a = __builtin_bit_cast(unsigned short, __float2bfloat16(lo));
    unsigned b = __builtin_bit_cast(unsigned short, __float2bfloat16(hi));
    return a | (b << 16);
}

// ---------------- LayerNorm (one block per row, C=1024, 256 threads) ----------------
__device__ __forceinline__ void stv(float* p, float v) { *p = v; }
__device__ __forceinline__ void stv(bf16* p, float v) { *p = __float2bfloat16(v); }

template<typename OutT>
__global__ __launch_bounds__(256) void ln_kernel(const float* __restrict__ x,
                                                 const float* __restrict__ w,
                                                 const float* __restrict__ b,
                                                 OutT* __restrict__ out) {
    int row = blockIdx.x;
    const float* xr = x + (size_t)row * C_;
    int t = threadIdx.x;
    float4 v = *(const float4*)(xr + t * 4);

    float s = v.x + v.y + v.z + v.w;
#pragma unroll
    for (int o = 32; o >= 1; o >>= 1) s += __shfl_xor(s, o);
    __shared__ float red[4];
    int wid = t >> 6, lane = t & 63;
    if (lane == 0) red[wid] = s;
    __syncthreads();
    float mean = (red[0] + red[1] + red[2] + red[3]) * (1.0f / C_);
    __syncthreads();

    float dx = v.x - mean, dy = v.y - mean, dz = v.z - mean, dw = v.w - mean;
    float ss = dx * dx + dy * dy + dz * dz + dw * dw;
#pragma unroll
    for (int o = 32; o >= 1; o >>= 1) ss += __shfl_xor(ss, o);
    if (lane == 0) red[wid] = ss;
    __syncthreads();
    float var = (red[0] + red[1] + red[2] + red[3]) * (1.0f / C_);
    float rs = rsqrtf(var + 1e-5f);

    float4 wv = *(const float4*)(w + t * 4);
    float4 bv = *(const float4*)(b + t * 4);
    OutT* orow = out + (size_t)row * C_;
    stv(orow + t * 4 + 0, dx * rs * wv.x + bv.x);
    stv(orow + t * 4 + 1, dy * rs * wv.y + bv.y);
    stv(orow + t * 4 + 2, dz * rs * wv.z + bv.z);
    stv(orow + t * 4 + 3, dw * rs * wv.w + bv.w);
}

// ---------- fp32 [Kd][Nd] -> bf16 [Nd][Kd] transpose+convert, z batches up to 3 ----------
__global__ __launch_bounds__(256) void transpose_k(const float* __restrict__ W0,
                                                   const float* __restrict__ W1,
                                                   const float* __restrict__ W2,
                                                   bf16* __restrict__ Wt, int Kd, int Nd) {
    const float* W = (blockIdx.z == 0) ? W0 : (blockIdx.z == 1) ? W1 : W2;
    bf16* dst = Wt + (size_t)blockIdx.z * Kd * Nd;
    __shared__ float tile[32][33];
    int tx = threadIdx.x, ty = threadIdx.y;          // (32, 8)
    int gx = blockIdx.x * 32, gy = blockIdx.y * 32;  // gx over Nd, gy over Kd
#pragma unroll
    for (int i = 0; i < 32; i += 8)
        tile[ty + i][tx] = W[(size_t)(gy + ty + i) * Nd + gx + tx];
    __syncthreads();
#pragma unroll
    for (int i = 0; i < 32; i += 8)
        dst[(size_t)(gx + ty + i) * Kd + gy + tx] = __float2bfloat16(tile[tx][ty + i]);
}

// ---------------- MFMA GEMM tile, m97-class: BK=64, global_load_lds(16B), linear LDS ----------------
template<int BM, int BN, int EPI>
__device__ __forceinline__ void gemm_tile(const bf16* __restrict__ A_, int lda,
                                          const bf16* __restrict__ Bt_, int ldb,
                                          const float* __restrict__ bias,
                                          void* __restrict__ C0, void* __restrict__ C1,
                                          void* __restrict__ C2, int ldc,
                                          int K, int bm0, int bn0) {
    constexpr int WM = BM / 2, WN = BN / 2, MR = WM / 16, NR = WN / 16;
    __shared__ __align__(16) short As[BM * 64];
    __shared__ __align__(16) short Bs[BN * 64];
    const short* Ap = (const short*)A_;
    const short* Bp = (const short*)Bt_;

    int tid = threadIdx.x;
    int wid = tid >> 6, lane = tid & 63, lr = lane & 15, lg = lane >> 4;
    int wr = wid >> 1, wc = wid & 1;

    f32x4 acc[MR][NR];
    const f32x4 z4 = {0.f, 0.f, 0.f, 0.f};
#pragma unroll
    for (int m = 0; m < MR; ++m)
#pragma unroll
        for (int n = 0; n < NR; ++n) acc[m][n] = z4;

    for (int k0 = 0; k0 < K; k0 += 64) {
        __syncthreads();
#pragma unroll
        for (int i = 0; i < BM / 32; ++i) {
            int e = (i * 256 + tid) * 8;
            gload16(Ap + (size_t)(bm0 + (e >> 6)) * lda + (k0 + (e & 63)),
                    As + (i * 256 + wid * 64) * 8);
        }
#pragma unroll
        for (int i = 0; i < BN / 32; ++i) {
            int e = (i * 256 + tid) * 8;
            gload16(Bp + (size_t)(bn0 + (e >> 6)) * ldb + (k0 + (e & 63)),
                    Bs + (i * 256 + wid * 64) * 8);
        }
        asm volatile("s_waitcnt vmcnt(0)" ::: "memory");
        __syncthreads();

        s16x8 af[MR][2], bfv[NR][2];
#pragma unroll
        for (int m = 0; m < MR; ++m)
#pragma unroll
            for (int ks = 0; ks < 2; ++ks)
                af[m][ks] = *(const s16x8*)&As[(wr * WM + m * 16 + lr) * 64 + ks * 32 + lg * 8];
#pragma unroll
        for (int n = 0; n < NR; ++n)
#pragma unroll
            for (int ks = 0; ks < 2; ++ks)
                bfv[n][ks] = *(const s16x8*)&Bs[(wc * WN + n * 16 + lr) * 64 + ks * 32 + lg * 8];
#pragma unroll
        for (int m = 0; m < MR; ++m)
#pragma unroll
            for (int n = 0; n < NR; ++n)
#pragma unroll
                for (int ks = 0; ks < 2; ++ks)
                    acc[m][n] = __builtin_amdgcn_mfma_f32_16x16x32_bf16(af[m][ks], bfv[n][ks],
                                                                        acc[m][n], 0, 0, 0);
    }

    // epilogue: C/D layout col=lane&15, row=(lane>>4)*4+i   [verified m89]
#pragma unroll
    for (int m = 0; m < MR; ++m)
#pragma unroll
        for (int n = 0; n < NR; ++n)
#pragma unroll
            for (int i = 0; i < 4; ++i) {
                int gm = bm0 + wr * WM + m * 16 + lg * 4 + i;
                int gn = bn0 + wc * WN + n * 16 + lr;
                float v = acc[m][n][i];
                if constexpr (EPI == EPI_QKV) {
                    float vb = v + bias[gn];
                    if (gn < 2048) {
                        bf16* dst = (gn < 1024) ? (bf16*)C0 : (bf16*)C1;
                        dst[(size_t)gm * C_ + (gn & 1023)] = __float2bfloat16(vb);
                    } else {
                        int d = gn - 2048, bb = gm >> 10, tt = gm & 1023;
                        ((bf16*)C2)[((size_t)(bb * 1024 + d)) * T_ + tt] = __float2bfloat16(vb);
                    }
                } else if constexpr (EPI == EPI_RESID) {
                    float* cp = (float*)C0 + (size_t)gm * ldc + gn;
                    *cp = *cp + v + bias[gn];
                } else if constexpr (EPI == EPI_GELU) {
                    float xg = v + bias[gn];
                    float g = 0.5f * xg * (1.0f + erff(xg * 0.70710678118654752f));
                    ((bf16*)C0)[(size_t)gm * ldc + gn] = __float2bfloat16(g);
                } else if constexpr (EPI == EPI_PARTIAL) {
                    ((float*)C0)[(size_t)gm * ldc + gn] = v;
                }
            }
}

template<int BM, int BN, int EPI>
__global__ __launch_bounds__(256) void gemm_k(const bf16* A, int lda, const bf16* Bt, int ldb,
                                              const float* bias, void* C0, int ldc, int K) {
    gemm_tile<BM, BN, EPI>(A, lda, Bt, ldb, bias, C0, nullptr, nullptr, ldc, K,
                           blockIdx.y * BM, blockIdx.x * BN);
}

__global__ __launch_bounds__(256) void gemm_qkv_k(const bf16* a, const bf16* wt, const float* bqkv,
                                                  bf16* qb, bf16* kb, bf16* vT) {
    gemm_tile<128, 128, EPI_QKV>(a, C_, wt, C_, bqkv, qb, kb, vT, 0, C_,
                                 blockIdx.y * 128, blockIdx.x * 128);
}

__global__ __launch_bounds__(256) void gemm_splitk_k(const bf16* A, int lda, const bf16* Bt, int ldb,
                                                     float* part, int Ksl) {
    int z = blockIdx.z;
    gemm_tile<128, 128, EPI_PARTIAL>(A + (size_t)z * Ksl, lda, Bt + (size_t)z * Ksl, ldb, nullptr,
                                     part + (size_t)z * M_ * C_, nullptr, nullptr, C_, Ksl,
                                     blockIdx.y * 128, blockIdx.x * 128);
}

__global__ __launch_bounds__(256) void combine_k(float* __restrict__ h, const float* __restrict__ part,
                                                 const float* __restrict__ bias) {
    int i = blockIdx.x * 256 + threadIdx.x;
    float4 a = ((const float4*)part)[i];
    float4 b = ((const float4*)(part + (size_t)M_ * C_))[i];
    float4 hv = ((const float4*)h)[i];
    float4 bb = ((const float4*)bias)[i & (C_ / 4 - 1)];
    hv.x += a.x + b.x + bb.x; hv.y += a.y + b.y + bb.y;
    hv.z += a.z + b.z + bb.z; hv.w += a.w + b.w + bb.w;
    ((float4*)h)[i] = hv;
}

// ---------------- Flash attention: one block per (64-q tile, head pair) ----------------
// 4 waves x 16 q-cols. S^T = mfma(K,Q) so kv-reduction is in-lane + 2 shuffles.
// P redistributed in-register to PV B-frag; O^T = mfma(V^T, P). KV tile 64, LDS swizzled.
__global__ __launch_bounds__(256) void flash_k(const bf16* __restrict__ qb,
                                               const bf16* __restrict__ kb,
                                               const bf16* __restrict__ vT,
                                               bf16* __restrict__ yb) {
    int qt = blockIdx.x, pair = blockIdx.y;
    int bb = pair >> 4, hh = pair & 15;
    __shared__ __align__(16) short Ks[64 * 64];
    __shared__ __align__(16) short Vs[64 * 64];

    int tid = threadIdx.x, wid = tid >> 6, lane = tid & 63, lr = lane & 15, lg = lane >> 4;
    int qrow = qt * 64 + wid * 16 + lr;  // this lane's q column (S^T col = lr)

    // Q fragment (B-operand of QK^T), hoisted: lane = q-row qrow, k = ks*32+lg*8
    const short* qp = (const short*)qb + ((size_t)(bb * T_ + qrow)) * C_ + hh * 64;
    s16x8 qf[2];
    qf[0] = *(const s16x8*)(qp + lg * 8);
    qf[1] = *(const s16x8*)(qp + 32 + lg * 8);

    const short* kbase = (const short*)kb + ((size_t)bb * T_) * C_ + hh * 64;  // row kv, stride C_
    const short* vbase = (const short*)vT + ((size_t)pair * 64) * T_;          // row d, stride T_

    f32x4 oacc[4];
    const f32x4 z4 = {0.f, 0.f, 0.f, 0.f};
#pragma unroll
    for (int m = 0; m < 4; ++m) oacc[m] = z4;
    float mrun = -INFINITY, lrun = 0.f;

    // shuffle source lanes for P redistribution (per target u32 r)
    int srcl[4];
#pragma unroll
    for (int r = 0; r < 4; ++r) srcl[r] = ((((lg << 3) + 2 * r) & 15) >> 2) * 16 + lr;
    bool hihalf = lg >= 2;
    int swz = lr & 7;  // LDS read swizzle key (row&7 == lr&7 for all row=mr*16+lr)

    for (int t = 0; t <= qt; ++t) {
        int kv0 = t * 64;
        __syncthreads();
#pragma unroll
        for (int i = 0; i < 2; ++i) {
            int slot = i * 256 + tid;
            int row = slot >> 3, cs = (slot & 7) ^ (row & 7);
            gload16(kbase + (size_t)(kv0 + row) * C_ + cs * 8, Ks + (i * 256 + wid * 64) * 8);
        }
#pragma unroll
        for (int i = 0; i < 2; ++i) {
            int slot = i * 256 + tid;
            int row = slot >> 3, cs = (slot & 7) ^ (row & 7);
            gload16(vbase + (size_t)row * T_ + kv0 + cs * 8, Vs + (i * 256 + wid * 64) * 8);
        }
        asm volatile("s_waitcnt vmcnt(0)" ::: "memory");
        __syncthreads();

        // S^T: rows kv (frag mr: kv = mr*16 + lg*4 + i), col q = lr
        f32x4 sacc[4];
#pragma unroll
        for (int m = 0; m < 4; ++m) sacc[m] = z4;
#pragma unroll
        for (int ks = 0; ks < 2; ++ks)
#pragma unroll
            for (int mr = 0; mr < 4; ++mr) {
                s16x8 kf = *(const s16x8*)&Ks[(mr * 16 + lr) * 64 + (((ks * 4 + lg) ^ swz) * 8)];
                sacc[mr] = __builtin_amdgcn_mfma_f32_16x16x32_bf16(kf, qf[ks], sacc[mr], 0, 0, 0);
            }

        // scale + causal mask (only the diagonal tile needs it)
        float p[4][4];
        bool diag = (t == qt);
#pragma unroll
        for (int mr = 0; mr < 4; ++mr)
#pragma unroll
            for (int i = 0; i < 4; ++i) {
                float s = sacc[mr][i] * 0.125f;
                if (diag && (kv0 + mr * 16 + lg * 4 + i) > qrow) s = -1e30f;
                p[mr][i] = s;
            }

        // online softmax: max/sum over kv = in-lane(16) + shfl over lg
        float tmax = p[0][0];
#pragma unroll
        for (int mr = 0; mr < 4; ++mr)
#pragma unroll
            for (int i = 0; i < 4; ++i) tmax = fmaxf(tmax, p[mr][i]);
        tmax = fmaxf(tmax, __shfl_xor(tmax, 16));
        tmax = fmaxf(tmax, __shfl_xor(tmax, 32));

        float mnew = fmaxf(mrun, tmax);
        float corr = __expf(mrun - mnew);
        float tsum = 0.f;
#pragma unroll
        for (int mr = 0; mr < 4; ++mr)
#pragma unroll
            for (int i = 0; i < 4; ++i) {
                p[mr][i] = __expf(p[mr][i] - mnew);
                tsum += p[mr][i];
            }
        tsum += __shfl_xor(tsum, 16);
        tsum += __shfl_xor(tsum, 32);
        lrun = lrun * corr + tsum;
        mrun = mnew;
#pragma unroll
        for (int m = 0; m < 4; ++m)
#pragma unroll
            for (int i = 0; i < 4; ++i) oacc[m][i] *= corr;

        // pack P to bf16 pairs: pk[mr][0]=(kv 4lg,4lg+1), pk[mr][1]=(4lg+2,4lg+3)
        unsigned pk[4][2];
#pragma unroll
        for (int mr = 0; mr < 4; ++mr) {
            pk[mr][0] = packbf(p[mr][0], p[mr][1]);
            pk[mr][1] = packbf(p[mr][2], p[mr][3]);
        }

        // PV: O^T[d][q] += V^T-frag x P-frag, kv blocks b2 = 0,1
#pragma unroll
        for (int b2 = 0; b2 < 2; ++b2) {
            union { unsigned u[4]; s16x8 v; } pf;
#pragma unroll
            for (int r = 0; r < 4; ++r) {
                unsigned t0 = (unsigned)__shfl((int)pk[2 * b2][r & 1], srcl[r], 64);
                unsigned t1 = (unsigned)__shfl((int)pk[2 * b2 + 1][r & 1], srcl[r], 64);
                pf.u[r] = hihalf ? t1 : t0;
            }
#pragma unroll
            for (int mr = 0; mr < 4; ++mr) {
                s16x8 av = *(const s16x8*)&Vs[(mr * 16 + lr) * 64 + (((b2 * 4 + lg) ^ swz) * 8)];
                oacc[mr] = __builtin_amdgcn_mfma_f32_16x16x32_bf16(av, pf.v, oacc[mr], 0, 0, 0);
            }
        }
    }

    // epilogue: O^T row d = mr*16+lg*4+i, col q = lr -> y[b*T+qrow][h*64+d]
    float linv = 1.0f / lrun;
    bf16* yrow = yb + ((size_t)(bb * T_ + qrow)) * C_ + hh * 64;
#pragma unroll
    for (int mr = 0; mr < 4; ++mr) {
        union { unsigned short us[4]; unsigned long long u64; } w;
#pragma unroll
        for (int i = 0; i < 4; ++i)
            w.us[i] = __builtin_bit_cast(unsigned short, __float2bfloat16(oacc[mr][i] * linv));
        *(unsigned long long*)(yrow + mr * 16 + lg * 4) = w.u64;
    }
}

extern "C" void kernel_launch(void* const* d_in, const int* in_sizes, int n_in,
                              void* d_out, int out_size, void* d_ws, size_t ws_size,
                              hipStream_t stream) {
    const float* x     = (const float*)d_in[0];
    const float* Wq    = (const float*)d_in[1];
    const float* Wk    = (const float*)d_in[2];
    const float* Wv    = (const float*)d_in[3];
    const float* Wp    = (const float*)d_in[4];
    const float* bq    = (const float*)d_in[5];
    const float* bk    = (const float*)d_in[6];
    const float* bv    = (const float*)d_in[7];
    const float* bp    = (const float*)d_in[8];
    const float* ln1w  = (const float*)d_in[9];
    const float* ln1b  = (const float*)d_in[10];
    const float* ln2w  = (const float*)d_in[11];
    const float* ln2b  = (const float*)d_in[12];
    const float* W1    = (const float*)d_in[13];
    const float* b1    = (const float*)d_in[14];
    const float* W2    = (const float*)d_in[15];
    const float* b2    = (const float*)d_in[16];
    const float* lnfw  = (const float*)d_in[17];
    const float* lnfb  = (const float*)d_in[18];

    float* h = (float*)d_out;  // residual stream lives in d_out (fp32 [M,C])
    hipMemcpyAsync(h, x, (size_t)M_ * C_ * 4, hipMemcpyDeviceToDevice, stream);

    // ---- workspace carve ----
    char* base = (char*)d_ws;
    size_t off = 0;
    auto carve = [&](size_t bytes) {
        char* r = base + off;
        off += (bytes + 255) & ~(size_t)255;
        return r;
    };
    bf16*  a    = (bf16*)carve((size_t)M_ * C_ * 2);
    bf16*  qb   = (bf16*)carve((size_t)M_ * C_ * 2);
    bf16*  kb   = (bf16*)carve((size_t)M_ * C_ * 2);
    bf16*  vT   = (bf16*)carve((size_t)M_ * C_ * 2);   // [B*H*64, T]
    bf16*  yb   = (bf16*)carve((size_t)M_ * C_ * 2);
    bf16*  hid  = (bf16*)carve((size_t)M_ * FF * 2);
    bf16*  wt   = (bf16*)carve((size_t)C_ * FF * 2);   // transposed-weight staging (8MB)
    float* bqkv = (float*)carve(3 * C_ * 4);
    float* part = (float*)carve((size_t)2 * M_ * C_ * 4);  // split-K partials (16MB)

    dim3 tb(256);
    dim3 tpb(32, 8);

    for (int l = 0; l < L_; ++l) {
        // LN1 -> a (bf16)
        ln_kernel<bf16><<<M_, tb, 0, stream>>>(h, ln1w + l * C_, ln1b + l * C_, a);

        // QKV fused: transpose Wq|Wk|Wv -> wt [3C][C], pack biases, one N=3072 GEMM
        transpose_k<<<dim3(32, 32, 3), tpb, 0, stream>>>(Wq + (size_t)l * C_ * C_,
                                                         Wk + (size_t)l * C_ * C_,
                                                         Wv + (size_t)l * C_ * C_, wt, C_, C_);
        hipMemcpyAsync(bqkv,          bq + l * C_, C_ * 4, hipMemcpyDeviceToDevice, stream);
        hipMemcpyAsync(bqkv + C_,     bk + l * C_, C_ * 4, hipMemcpyDeviceToDevice, stream);
        hipMemcpyAsync(bqkv + 2 * C_, bv + l * C_, C_ * 4, hipMemcpyDeviceToDevice, stream);
        gemm_qkv_k<<<dim3(24, 16), tb, 0, stream>>>(a, wt, bqkv, qb, kb, vT);

        // flash attention: (16 q-tiles, 32 head-pairs)
        flash_k<<<dim3(16, 32), tb, 0, stream>>>(qb, kb, vT, yb);

        // out proj + residual into h
        transpose_k<<<dim3(32, 32, 1), tpb, 0, stream>>>(Wp + (size_t)l * C_ * C_, nullptr, nullptr,
                                                         wt, C_, C_);
        gemm_k<64, 128, EPI_RESID><<<dim3(8, 32), tb, 0, stream>>>(yb, C_, wt, C_, bp + l * C_,
                                                                   h, C_, C_);

        // LN2 -> a
        ln_kernel<bf16><<<M_, tb, 0, stream>>>(h, ln2w + l * C_, ln2b + l * C_, a);

        // MLP up + GELU -> hid
        transpose_k<<<dim3(FF / 32, C_ / 32, 1), tpb, 0, stream>>>(W1 + (size_t)l * C_ * FF, nullptr,
                                                                   nullptr, wt, C_, FF);
        gemm_k<128, 128, EPI_GELU><<<dim3(FF / 128, M_ / 128), tb, 0, stream>>>(a, C_, wt, C_,
                                                                                b1 + l * FF, hid, FF, C_);

        // MLP down: split-K=2 into partials, then combine (+bias +residual)
        transpose_k<<<dim3(C_ / 32, FF / 32, 1), tpb, 0, stream>>>(W2 + (size_t)l * FF * C_, nullptr,
                                                                   nullptr, wt, FF, C_);
        gemm_splitk_k<<<dim3(8, 16, 2), tb, 0, stream>>>(hid, FF, wt, FF, part, FF / 2);
        combine_k<<<M_ * C_ / 1024, tb, 0, stream>>>(h, part, b2 + l * C_);
    }

    // final LN in place (fp32 out)
    ln_kernel<float><<<M_, tb, 0, stream>>>(h, lnfw, lnfb, h);
}

// Round 5
// 1671.129 us; speedup vs baseline: 1.4749x; 1.0309x over previous
//
#include <hip/hip_runtime.h>
#include <hip/hip_bf16.h>

#define L_ 8
#define H_ 16
#define C_ 1024
#define B_ 2
#define T_ 1024
#define M_ (B_*T_)   // 2048 rows
#define DH 64
#define FF (4*C_)    // 4096

typedef __hip_bfloat16 bf16;
typedef __attribute__((ext_vector_type(8))) short s16x8;
typedef __attribute__((ext_vector_type(4))) float f32x4;

enum { EPI_QKV = 0, EPI_RESID = 1, EPI_GELU = 2, EPI_PARTIAL = 3 };

__device__ __forceinline__ void gload16(const void* g, void* l) {
    __builtin_amdgcn_global_load_lds(
        (const __attribute__((address_space(1))) unsigned int*)g,
        (__attribute__((address_space(3))) unsigned int*)l, 16, 0, 0);
}

__device__ __forceinline__ unsigned packbf(float lo, float hi) {
    unsigned a = __builtin_bit_cast(unsigned short, __float2bfloat16(lo));
    unsigned b = __builtin_bit_cast(unsigned short, __float2bfloat16(hi));
    return a | (b << 16);
}

// ---------------- LayerNorm (one block per row, C=1024, 256 threads) ----------------
__device__ __forceinline__ void stv(float* p, float v) { *p = v; }
__device__ __forceinline__ void stv(bf16* p, float v) { *p = __float2bfloat16(v); }

template<typename OutT>
__global__ __launch_bounds__(256) void ln_kernel(const float* __restrict__ x,
                                                 const float* __restrict__ w,
                                                 const float* __restrict__ b,
                                                 OutT* __restrict__ out) {
    int row = blockIdx.x;
    const float* xr = x + (size_t)row * C_;
    int t = threadIdx.x;
    float4 v = *(const float4*)(xr + t * 4);

    float s = v.x + v.y + v.z + v.w;
#pragma unroll
    for (int o = 32; o >= 1; o >>= 1) s += __shfl_xor(s, o);
    __shared__ float red[4];
    int wid = t >> 6, lane = t & 63;
    if (lane == 0) red[wid] = s;
    __syncthreads();
    float mean = (red[0] + red[1] + red[2] + red[3]) * (1.0f / C_);
    __syncthreads();

    float dx = v.x - mean, dy = v.y - mean, dz = v.z - mean, dw = v.w - mean;
    float ss = dx * dx + dy * dy + dz * dz + dw * dw;
#pragma unroll
    for (int o = 32; o >= 1; o >>= 1) ss += __shfl_xor(ss, o);
    if (lane == 0) red[wid] = ss;
    __syncthreads();
    float var = (red[0] + red[1] + red[2] + red[3]) * (1.0f / C_);
    float rs = rsqrtf(var + 1e-5f);

    float4 wv = *(const float4*)(w + t * 4);
    float4 bv = *(const float4*)(b + t * 4);
    OutT* orow = out + (size_t)row * C_;
    stv(orow + t * 4 + 0, dx * rs * wv.x + bv.x);
    stv(orow + t * 4 + 1, dy * rs * wv.y + bv.y);
    stv(orow + t * 4 + 2, dz * rs * wv.z + bv.z);
    stv(orow + t * 4 + 3, dw * rs * wv.w + bv.w);
}

// ---- all-weights transpose for one layer: fp32 [Kd][Nd] -> bf16 [Nd][Kd] into wt slab ----
// wt layout (bf16 elems): [0,3M) qkv, [3M,4M) proj, [4M,8M) up, [8M,12M) down
__global__ __launch_bounds__(256) void transpose_all_k(const float* __restrict__ Wq,
                                                       const float* __restrict__ Wk,
                                                       const float* __restrict__ Wv,
                                                       const float* __restrict__ Wp,
                                                       const float* __restrict__ W1,
                                                       const float* __restrict__ W2,
                                                       bf16* __restrict__ wt) {
    int idx = blockIdx.x;
    const float* W; bf16* dst; int Kd, Nd;
    if (idx < 3072) {
        int z = idx >> 10;
        W = (z == 0) ? Wq : (z == 1) ? Wk : Wv;
        dst = wt + (size_t)z * 1048576; Kd = C_; Nd = C_; idx &= 1023;
    } else if (idx < 4096) {
        W = Wp; dst = wt + (size_t)3 * 1048576; Kd = C_; Nd = C_; idx -= 3072;
    } else if (idx < 8192) {
        W = W1; dst = wt + (size_t)4 * 1048576; Kd = C_; Nd = FF; idx -= 4096;
    } else {
        W = W2; dst = wt + (size_t)8 * 1048576; Kd = FF; Nd = C_; idx -= 8192;
    }
    int ntx = Nd / 32;
    int gx = (idx & (ntx - 1)) * 32, gy = (idx / ntx) * 32;

    __shared__ float tile[32][33];
    int tx = threadIdx.x, ty = threadIdx.y;  // (32, 8)
#pragma unroll
    for (int i = 0; i < 32; i += 8)
        tile[ty + i][tx] = W[(size_t)(gy + ty + i) * Nd + gx + tx];
    __syncthreads();
#pragma unroll
    for (int i = 0; i < 32; i += 8)
        dst[(size_t)(gx + ty + i) * Kd + gy + tx] = __float2bfloat16(tile[tx][ty + i]);
}

// ---------------- MFMA GEMM tile, m97-class: BK=64, global_load_lds(16B), linear LDS ----------------
template<int BM, int BN, int EPI>
__device__ __forceinline__ void gemm_tile(const bf16* __restrict__ A_, int lda,
                                          const bf16* __restrict__ Bt_, int ldb,
                                          const float* __restrict__ bias,
                                          const float* __restrict__ bias2,
                                          const float* __restrict__ bias3,
                                          void* __restrict__ C0, void* __restrict__ C1,
                                          void* __restrict__ C2, int ldc,
                                          int K, int bm0, int bn0) {
    constexpr int WM = BM / 2, WN = BN / 2, MR = WM / 16, NR = WN / 16;
    __shared__ __align__(16) short As[BM * 64];
    __shared__ __align__(16) short Bs[BN * 64];
    const short* Ap = (const short*)A_;
    const short* Bp = (const short*)Bt_;

    int tid = threadIdx.x;
    int wid = tid >> 6, lane = tid & 63, lr = lane & 15, lg = lane >> 4;
    int wr = wid >> 1, wc = wid & 1;

    f32x4 acc[MR][NR];
    const f32x4 z4 = {0.f, 0.f, 0.f, 0.f};
#pragma unroll
    for (int m = 0; m < MR; ++m)
#pragma unroll
        for (int n = 0; n < NR; ++n) acc[m][n] = z4;

    for (int k0 = 0; k0 < K; k0 += 64) {
        __syncthreads();
#pragma unroll
        for (int i = 0; i < BM / 32; ++i) {
            int e = (i * 256 + tid) * 8;
            gload16(Ap + (size_t)(bm0 + (e >> 6)) * lda + (k0 + (e & 63)),
                    As + (i * 256 + wid * 64) * 8);
        }
#pragma unroll
        for (int i = 0; i < BN / 32; ++i) {
            int e = (i * 256 + tid) * 8;
            gload16(Bp + (size_t)(bn0 + (e >> 6)) * ldb + (k0 + (e & 63)),
                    Bs + (i * 256 + wid * 64) * 8);
        }
        asm volatile("s_waitcnt vmcnt(0)" ::: "memory");
        __syncthreads();

        s16x8 af[MR][2], bfv[NR][2];
#pragma unroll
        for (int m = 0; m < MR; ++m)
#pragma unroll
            for (int ks = 0; ks < 2; ++ks)
                af[m][ks] = *(const s16x8*)&As[(wr * WM + m * 16 + lr) * 64 + ks * 32 + lg * 8];
#pragma unroll
        for (int n = 0; n < NR; ++n)
#pragma unroll
            for (int ks = 0; ks < 2; ++ks)
                bfv[n][ks] = *(const s16x8*)&Bs[(wc * WN + n * 16 + lr) * 64 + ks * 32 + lg * 8];
#pragma unroll
        for (int m = 0; m < MR; ++m)
#pragma unroll
            for (int n = 0; n < NR; ++n)
#pragma unroll
                for (int ks = 0; ks < 2; ++ks)
                    acc[m][n] = __builtin_amdgcn_mfma_f32_16x16x32_bf16(af[m][ks], bfv[n][ks],
                                                                        acc[m][n], 0, 0, 0);
    }

    // epilogue: C/D layout col=lane&15, row=(lane>>4)*4+i   [verified m89]
#pragma unroll
    for (int m = 0; m < MR; ++m)
#pragma unroll
        for (int n = 0; n < NR; ++n)
#pragma unroll
            for (int i = 0; i < 4; ++i) {
                int gm = bm0 + wr * WM + m * 16 + lg * 4 + i;
                int gn = bn0 + wc * WN + n * 16 + lr;
                float v = acc[m][n][i];
                if constexpr (EPI == EPI_QKV) {
                    if (gn < 1024) {
                        ((bf16*)C0)[(size_t)gm * C_ + gn] = __float2bfloat16(v + bias[gn]);
                    } else if (gn < 2048) {
                        ((bf16*)C1)[(size_t)gm * C_ + (gn - 1024)] =
                            __float2bfloat16(v + bias2[gn - 1024]);
                    } else {
                        int d = gn - 2048, bb = gm >> 10, tt = gm & 1023;
                        ((bf16*)C2)[((size_t)(bb * 1024 + d)) * T_ + tt] =
                            __float2bfloat16(v + bias3[d]);
                    }
                } else if constexpr (EPI == EPI_RESID) {
                    float* cp = (float*)C0 + (size_t)gm * ldc + gn;
                    *cp = *cp + v + bias[gn];
                } else if constexpr (EPI == EPI_GELU) {
                    float xg = v + bias[gn];
                    float g = 0.5f * xg * (1.0f + erff(xg * 0.70710678118654752f));
                    ((bf16*)C0)[(size_t)gm * ldc + gn] = __float2bfloat16(g);
                } else if constexpr (EPI == EPI_PARTIAL) {
                    ((float*)C0)[(size_t)gm * ldc + gn] = v;
                }
            }
}

template<int BM, int BN, int EPI>
__global__ __launch_bounds__(256) void gemm_k(const bf16* A, int lda, const bf16* Bt, int ldb,
                                              const float* bias, void* C0, int ldc, int K) {
    gemm_tile<BM, BN, EPI>(A, lda, Bt, ldb, bias, nullptr, nullptr, C0, nullptr, nullptr, ldc, K,
                           blockIdx.y * BM, blockIdx.x * BN);
}

__global__ __launch_bounds__(256) void gemm_qkv_k(const bf16* a, const bf16* wt,
                                                  const float* bq, const float* bk, const float* bv,
                                                  bf16* qb, bf16* kb, bf16* vT) {
    gemm_tile<128, 128, EPI_QKV>(a, C_, wt, C_, bq, bk, bv, qb, kb, vT, 0, C_,
                                 blockIdx.y * 128, blockIdx.x * 128);
}

__global__ __launch_bounds__(256) void gemm_splitk_k(const bf16* A, int lda, const bf16* Bt, int ldb,
                                                     float* part, int Ksl) {
    int z = blockIdx.z;
    gemm_tile<128, 128, EPI_PARTIAL>(A + (size_t)z * Ksl, lda, Bt + (size_t)z * Ksl, ldb,
                                     nullptr, nullptr, nullptr,
                                     part + (size_t)z * M_ * C_, nullptr, nullptr, C_, Ksl,
                                     blockIdx.y * 128, blockIdx.x * 128);
}

// ---- split-K combine (+bias +residual into h), optionally fused next-layer LN1 -> a ----
template<bool LN>
__global__ __launch_bounds__(256) void combine_ln_k(float* __restrict__ h,
                                                    const float* __restrict__ part,
                                                    const float* __restrict__ bias,
                                                    const float* __restrict__ lw,
                                                    const float* __restrict__ lb,
                                                    bf16* __restrict__ aout) {
    int row = blockIdx.x, t = threadIdx.x;
    float4 p0 = ((const float4*)(part + (size_t)row * C_))[t];
    float4 p1 = ((const float4*)(part + (size_t)M_ * C_ + (size_t)row * C_))[t];
    float4 hv = ((const float4*)(h + (size_t)row * C_))[t];
    float4 bb = ((const float4*)bias)[t];
    hv.x += p0.x + p1.x + bb.x; hv.y += p0.y + p1.y + bb.y;
    hv.z += p0.z + p1.z + bb.z; hv.w += p0.w + p1.w + bb.w;
    ((float4*)(h + (size_t)row * C_))[t] = hv;

    if constexpr (LN) {
        float s = hv.x + hv.y + hv.z + hv.w;
#pragma unroll
        for (int o = 32; o >= 1; o >>= 1) s += __shfl_xor(s, o);
        __shared__ float red[4];
        int wid = t >> 6, lane = t & 63;
        if (lane == 0) red[wid] = s;
        __syncthreads();
        float mean = (red[0] + red[1] + red[2] + red[3]) * (1.0f / C_);
        __syncthreads();
        float dx = hv.x - mean, dy = hv.y - mean, dz = hv.z - mean, dw = hv.w - mean;
        float ss = dx * dx + dy * dy + dz * dz + dw * dw;
#pragma unroll
        for (int o = 32; o >= 1; o >>= 1) ss += __shfl_xor(ss, o);
        if (lane == 0) red[wid] = ss;
        __syncthreads();
        float var = (red[0] + red[1] + red[2] + red[3]) * (1.0f / C_);
        float rs = rsqrtf(var + 1e-5f);
        float4 wv = ((const float4*)lw)[t];
        float4 bv = ((const float4*)lb)[t];
        bf16* ar = aout + (size_t)row * C_;
        ar[t * 4 + 0] = __float2bfloat16(dx * rs * wv.x + bv.x);
        ar[t * 4 + 1] = __float2bfloat16(dy * rs * wv.y + bv.y);
        ar[t * 4 + 2] = __float2bfloat16(dz * rs * wv.z + bv.z);
        ar[t * 4 + 3] = __float2bfloat16(dw * rs * wv.w + bv.w);
    }
}

// ---------------- Flash attention: one block per (64-q tile, head pair) ----------------
// 4 waves x 16 q-cols. S^T = mfma(K,Q); P redistributed in-register; O^T = mfma(V^T, P).
// KV tile 64, double-buffered LDS (stage t+1 before computing t), swizzled gload/ds_read.
__global__ __launch_bounds__(256) void flash_k(const bf16* __restrict__ qb,
                                               const bf16* __restrict__ kb,
                                               const bf16* __restrict__ vT,
                                               bf16* __restrict__ yb) {
    int qt = blockIdx.x, pair = blockIdx.y;
    int bb = pair >> 4, hh = pair & 15;
    __shared__ __align__(16) short Ks[2][64 * 64];
    __shared__ __align__(16) short Vs[2][64 * 64];

    int tid = threadIdx.x, wid = tid >> 6, lane = tid & 63, lr = lane & 15, lg = lane >> 4;
    int qrow = qt * 64 + wid * 16 + lr;

    const short* qp = (const short*)qb + ((size_t)(bb * T_ + qrow)) * C_ + hh * 64;
    s16x8 qf[2];
    qf[0] = *(const s16x8*)(qp + lg * 8);
    qf[1] = *(const s16x8*)(qp + 32 + lg * 8);

    const short* kbase = (const short*)kb + ((size_t)bb * T_) * C_ + hh * 64;  // row kv, stride C_
    const short* vbase = (const short*)vT + ((size_t)pair * 64) * T_;          // row d, stride T_

    auto stage = [&](int bf, int t) {
        int kv0 = t * 64;
#pragma unroll
        for (int i = 0; i < 2; ++i) {
            int slot = i * 256 + tid;
            int row = slot >> 3, cs = (slot & 7) ^ (row & 7);
            gload16(kbase + (size_t)(kv0 + row) * C_ + cs * 8, &Ks[bf][(i * 256 + wid * 64) * 8]);
        }
#pragma unroll
        for (int i = 0; i < 2; ++i) {
            int slot = i * 256 + tid;
            int row = slot >> 3, cs = (slot & 7) ^ (row & 7);
            gload16(vbase + (size_t)row * T_ + kv0 + cs * 8, &Vs[bf][(i * 256 + wid * 64) * 8]);
        }
    };

    f32x4 oacc[4];
    const f32x4 z4 = {0.f, 0.f, 0.f, 0.f};
#pragma unroll
    for (int m = 0; m < 4; ++m) oacc[m] = z4;
    float mrun = -INFINITY, lrun = 0.f;

    int srcl[4];
#pragma unroll
    for (int r = 0; r < 4; ++r) srcl[r] = ((((lg << 3) + 2 * r) & 15) >> 2) * 16 + lr;
    bool hihalf = lg >= 2;
    int swz = lr & 7;

    stage(0, 0);
    asm volatile("s_waitcnt vmcnt(0)" ::: "memory");
    __syncthreads();
    int cur = 0;

    for (int t = 0; t <= qt; ++t) {
        int kv0 = t * 64;
        if (t < qt) stage(cur ^ 1, t + 1);  // prefetch next tile into the other buffer

        // S^T: rows kv (frag mr: kv = mr*16 + lg*4 + i), col q = lr
        f32x4 sacc[4];
#pragma unroll
        for (int m = 0; m < 4; ++m) sacc[m] = z4;
#pragma unroll
        for (int ks = 0; ks < 2; ++ks)
#pragma unroll
            for (int mr = 0; mr < 4; ++mr) {
                s16x8 kf = *(const s16x8*)&Ks[cur][(mr * 16 + lr) * 64 + (((ks * 4 + lg) ^ swz) * 8)];
                sacc[mr] = __builtin_amdgcn_mfma_f32_16x16x32_bf16(kf, qf[ks], sacc[mr], 0, 0, 0);
            }

        float p[4][4];
        bool diag = (t == qt);
#pragma unroll
        for (int mr = 0; mr < 4; ++mr)
#pragma unroll
            for (int i = 0; i < 4; ++i) {
                float s = sacc[mr][i] * 0.125f;
                if (diag && (kv0 + mr * 16 + lg * 4 + i) > qrow) s = -1e30f;
                p[mr][i] = s;
            }

        float tmax = p[0][0];
#pragma unroll
        for (int mr = 0; mr < 4; ++mr)
#pragma unroll
            for (int i = 0; i < 4; ++i) tmax = fmaxf(tmax, p[mr][i]);
        tmax = fmaxf(tmax, __shfl_xor(tmax, 16));
        tmax = fmaxf(tmax, __shfl_xor(tmax, 32));

        float mnew = fmaxf(mrun, tmax);
        float corr = __expf(mrun - mnew);
        float tsum = 0.f;
#pragma unroll
        for (int mr = 0; mr < 4; ++mr)
#pragma unroll
            for (int i = 0; i < 4; ++i) {
                p[mr][i] = __expf(p[mr][i] - mnew);
                tsum += p[mr][i];
            }
        tsum += __shfl_xor(tsum, 16);
        tsum += __shfl_xor(tsum, 32);
        lrun = lrun * corr + tsum;
        mrun = mnew;
#pragma unroll
        for (int m = 0; m < 4; ++m)
#pragma unroll
            for (int i = 0; i < 4; ++i) oacc[m][i] *= corr;

        unsigned pk[4][2];
#pragma unroll
        for (int mr = 0; mr < 4; ++mr) {
            pk[mr][0] = packbf(p[mr][0], p[mr][1]);
            pk[mr][1] = packbf(p[mr][2], p[mr][3]);
        }

#pragma unroll
        for (int b2 = 0; b2 < 2; ++b2) {
            union { unsigned u[4]; s16x8 v; } pf;
#pragma unroll
            for (int r = 0; r < 4; ++r) {
                unsigned t0 = (unsigned)__shfl((int)pk[2 * b2][r & 1], srcl[r], 64);
                unsigned t1 = (unsigned)__shfl((int)pk[2 * b2 + 1][r & 1], srcl[r], 64);
                pf.u[r] = hihalf ? t1 : t0;
            }
#pragma unroll
            for (int mr = 0; mr < 4; ++mr) {
                s16x8 av = *(const s16x8*)&Vs[cur][(mr * 16 + lr) * 64 + (((b2 * 4 + lg) ^ swz) * 8)];
                oacc[mr] = __builtin_amdgcn_mfma_f32_16x16x32_bf16(av, pf.v, oacc[mr], 0, 0, 0);
            }
        }

        asm volatile("s_waitcnt vmcnt(0)" ::: "memory");  // drain this iter's prefetch
        __syncthreads();
        cur ^= 1;
    }

    float linv = 1.0f / lrun;
    bf16* yrow = yb + ((size_t)(bb * T_ + qrow)) * C_ + hh * 64;
#pragma unroll
    for (int mr = 0; mr < 4; ++mr) {
        union { unsigned short us[4]; unsigned long long u64; } w;
#pragma unroll
        for (int i = 0; i < 4; ++i)
            w.us[i] = __builtin_bit_cast(unsigned short, __float2bfloat16(oacc[mr][i] * linv));
        *(unsigned long long*)(yrow + mr * 16 + lg * 4) = w.u64;
    }
}

extern "C" void kernel_launch(void* const* d_in, const int* in_sizes, int n_in,
                              void* d_out, int out_size, void* d_ws, size_t ws_size,
                              hipStream_t stream) {
    const float* x     = (const float*)d_in[0];
    const float* Wq    = (const float*)d_in[1];
    const float* Wk    = (const float*)d_in[2];
    const float* Wv    = (const float*)d_in[3];
    const float* Wp    = (const float*)d_in[4];
    const float* bq    = (const float*)d_in[5];
    const float* bk    = (const float*)d_in[6];
    const float* bv    = (const float*)d_in[7];
    const float* bp    = (const float*)d_in[8];
    const float* ln1w  = (const float*)d_in[9];
    const float* ln1b  = (const float*)d_in[10];
    const float* ln2w  = (const float*)d_in[11];
    const float* ln2b  = (const float*)d_in[12];
    const float* W1    = (const float*)d_in[13];
    const float* b1    = (const float*)d_in[14];
    const float* W2    = (const float*)d_in[15];
    const float* b2    = (const float*)d_in[16];
    const float* lnfw  = (const float*)d_in[17];
    const float* lnfb  = (const float*)d_in[18];

    float* h = (float*)d_out;  // residual stream lives in d_out (fp32 [M,C])
    hipMemcpyAsync(h, x, (size_t)M_ * C_ * 4, hipMemcpyDeviceToDevice, stream);

    // ---- workspace carve ----
    char* base = (char*)d_ws;
    size_t off = 0;
    auto carve = [&](size_t bytes) {
        char* r = base + off;
        off += (bytes + 255) & ~(size_t)255;
        return r;
    };
    bf16*  a    = (bf16*)carve((size_t)M_ * C_ * 2);
    bf16*  qb   = (bf16*)carve((size_t)M_ * C_ * 2);
    bf16*  kb   = (bf16*)carve((size_t)M_ * C_ * 2);
    bf16*  vT   = (bf16*)carve((size_t)M_ * C_ * 2);      // [B*H*64, T]
    bf16*  yb   = (bf16*)carve((size_t)M_ * C_ * 2);
    bf16*  hid  = (bf16*)carve((size_t)M_ * FF * 2);
    bf16*  wt   = (bf16*)carve((size_t)12 * 1048576 * 2); // all-weights slab (24MB)
    float* part = (float*)carve((size_t)2 * M_ * C_ * 4); // split-K partials (16MB)

    dim3 tb(256);
    dim3 tpb(32, 8);

    // LN1 for layer 0 (later layers get it fused into combine_ln_k)
    ln_kernel<bf16><<<M_, tb, 0, stream>>>(h, ln1w, ln1b, a);

    for (int l = 0; l < L_; ++l) {
        // all 6 weight transposes in one launch
        transpose_all_k<<<12288, tpb, 0, stream>>>(Wq + (size_t)l * C_ * C_,
                                                   Wk + (size_t)l * C_ * C_,
                                                   Wv + (size_t)l * C_ * C_,
                                                   Wp + (size_t)l * C_ * C_,
                                                   W1 + (size_t)l * C_ * FF,
                                                   W2 + (size_t)l * FF * C_, wt);

        // QKV fused GEMM (biases read directly in epilogue)
        gemm_qkv_k<<<dim3(24, 16), tb, 0, stream>>>(a, wt, bq + l * C_, bk + l * C_, bv + l * C_,
                                                    qb, kb, vT);

        // flash attention
        flash_k<<<dim3(16, 32), tb, 0, stream>>>(qb, kb, vT, yb);

        // out proj + residual into h
        gemm_k<64, 128, EPI_RESID><<<dim3(8, 32), tb, 0, stream>>>(yb, C_, wt + (size_t)3 * 1048576,
                                                                   C_, bp + l * C_, h, C_, C_);

        // LN2 -> a
        ln_kernel<bf16><<<M_, tb, 0, stream>>>(h, ln2w + l * C_, ln2b + l * C_, a);

        // MLP up + GELU -> hid
        gemm_k<128, 128, EPI_GELU><<<dim3(FF / 128, M_ / 128), tb, 0, stream>>>(
            a, C_, wt + (size_t)4 * 1048576, C_, b1 + l * FF, hid, FF, C_);

        // MLP down: split-K=2 partials, then combine (+bias +residual [+next LN1])
        gemm_splitk_k<<<dim3(8, 16, 2), tb, 0, stream>>>(hid, FF, wt + (size_t)8 * 1048576, FF,
                                                         part, FF / 2);
        if (l < L_ - 1)
            combine_ln_k<true><<<M_, tb, 0, stream>>>(h, part, b2 + l * C_,
                                                      ln1w + (l + 1) * C_, ln1b + (l + 1) * C_, a);
        else
            combine_ln_k<false><<<M_, tb, 0, stream>>>(h, part, b2 + l * C_, nullptr, nullptr, nullptr);
    }

    // final LN in place (fp32 out)
    ln_kernel<float><<<M_, tb, 0, stream>>>(h, lnfw, lnfb, h);
}

// Round 6
// 1555.577 us; speedup vs baseline: 1.5845x; 1.0743x over previous
//
#include <hip/hip_runtime.h>
#include <hip/hip_bf16.h>

#define L_ 8
#define H_ 16
#define C_ 1024
#define B_ 2
#define T_ 1024
#define M_ (B_*T_)   // 2048 rows
#define DH 64
#define FF (4*C_)    // 4096

typedef __hip_bfloat16 bf16;
typedef __attribute__((ext_vector_type(8))) short s16x8;
typedef __attribute__((ext_vector_type(4))) float f32x4;
typedef __attribute__((ext_vector_type(16))) float f32x16;

enum { EPI_QKV = 0, EPI_RESID = 1, EPI_GELU = 2, EPI_PARTIAL = 3 };

#define WSLAB 12582912  // bf16 elems per layer in wt slab: 3M qkv | 1M proj | 4M up | 4M down

__device__ __forceinline__ void gload16(const void* g, void* l) {
    __builtin_amdgcn_global_load_lds(
        (const __attribute__((address_space(1))) unsigned int*)g,
        (__attribute__((address_space(3))) unsigned int*)l, 16, 0, 0);
}

__device__ __forceinline__ unsigned packbf(float lo, float hi) {
    unsigned a = __builtin_bit_cast(unsigned short, __float2bfloat16(lo));
    unsigned b = __builtin_bit_cast(unsigned short, __float2bfloat16(hi));
    return a | (b << 16);
}

// ---------------- LayerNorm (one block per row, C=1024, 256 threads) ----------------
__device__ __forceinline__ void stv(float* p, float v) { *p = v; }
__device__ __forceinline__ void stv(bf16* p, float v) { *p = __float2bfloat16(v); }

template<typename OutT>
__global__ __launch_bounds__(256) void ln_kernel(const float* __restrict__ x,
                                                 const float* __restrict__ w,
                                                 const float* __restrict__ b,
                                                 OutT* __restrict__ out) {
    int row = blockIdx.x;
    const float* xr = x + (size_t)row * C_;
    int t = threadIdx.x;
    float4 v = *(const float4*)(xr + t * 4);

    float s = v.x + v.y + v.z + v.w;
#pragma unroll
    for (int o = 32; o >= 1; o >>= 1) s += __shfl_xor(s, o);
    __shared__ float red[4];
    int wid = t >> 6, lane = t & 63;
    if (lane == 0) red[wid] = s;
    __syncthreads();
    float mean = (red[0] + red[1] + red[2] + red[3]) * (1.0f / C_);
    __syncthreads();

    float dx = v.x - mean, dy = v.y - mean, dz = v.z - mean, dw = v.w - mean;
    float ss = dx * dx + dy * dy + dz * dz + dw * dw;
#pragma unroll
    for (int o = 32; o >= 1; o >>= 1) ss += __shfl_xor(ss, o);
    if (lane == 0) red[wid] = ss;
    __syncthreads();
    float var = (red[0] + red[1] + red[2] + red[3]) * (1.0f / C_);
    float rs = rsqrtf(var + 1e-5f);

    float4 wv = *(const float4*)(w + t * 4);
    float4 bv = *(const float4*)(b + t * 4);
    OutT* orow = out + (size_t)row * C_;
    stv(orow + t * 4 + 0, dx * rs * wv.x + bv.x);
    stv(orow + t * 4 + 1, dy * rs * wv.y + bv.y);
    stv(orow + t * 4 + 2, dz * rs * wv.z + bv.z);
    stv(orow + t * 4 + 3, dw * rs * wv.w + bv.w);
}

// ---- weight transpose: fp32 [Kd][Nd] -> bf16 [Nd][Kd]; blockIdx.z = layer (rel) ----
__global__ __launch_bounds__(256) void transpose_all_k(const float* __restrict__ Wq,
                                                       const float* __restrict__ Wk,
                                                       const float* __restrict__ Wv,
                                                       const float* __restrict__ Wp,
                                                       const float* __restrict__ W1,
                                                       const float* __restrict__ W2,
                                                       bf16* __restrict__ wt, int l0) {
    int layer = l0 + blockIdx.z;
    bf16* slab = wt + (size_t)blockIdx.z * WSLAB;
    int idx = blockIdx.x;
    const float* W; bf16* dst; int Kd, Nd;
    if (idx < 3072) {
        int z = idx >> 10;
        W = ((z == 0) ? Wq : (z == 1) ? Wk : Wv) + (size_t)layer * C_ * C_;
        dst = slab + (size_t)z * 1048576; Kd = C_; Nd = C_; idx &= 1023;
    } else if (idx < 4096) {
        W = Wp + (size_t)layer * C_ * C_;
        dst = slab + (size_t)3 * 1048576; Kd = C_; Nd = C_; idx -= 3072;
    } else if (idx < 8192) {
        W = W1 + (size_t)layer * C_ * FF;
        dst = slab + (size_t)4 * 1048576; Kd = C_; Nd = FF; idx -= 4096;
    } else {
        W = W2 + (size_t)layer * FF * C_;
        dst = slab + (size_t)8 * 1048576; Kd = FF; Nd = C_; idx -= 8192;
    }
    int ntx = Nd / 32;
    int gx = (idx & (ntx - 1)) * 32, gy = (idx / ntx) * 32;

    __shared__ float tile[32][33];
    int tx = threadIdx.x, ty = threadIdx.y;  // (32, 8)
#pragma unroll
    for (int i = 0; i < 32; i += 8)
        tile[ty + i][tx] = W[(size_t)(gy + ty + i) * Nd + gx + tx];
    __syncthreads();
#pragma unroll
    for (int i = 0; i < 32; i += 8)
        dst[(size_t)(gx + ty + i) * Kd + gy + tx] = __float2bfloat16(tile[tx][ty + i]);
}

// ------------- MFMA GEMM tile: 32x32x16 bf16, BK=64, global_load_lds(16B), XOR-swizzled LDS -------------
// 256 threads = 2x2 waves; wave tile (BM/2)x(BN/2); each wave MRxNR 32x32 accs.
template<int BM, int BN, int EPI>
__device__ __forceinline__ void gemm_tile(const bf16* __restrict__ A_, int lda,
                                          const bf16* __restrict__ Bt_, int ldb,
                                          const float* __restrict__ bias,
                                          const float* __restrict__ bias2,
                                          const float* __restrict__ bias3,
                                          void* __restrict__ C0, void* __restrict__ C1,
                                          void* __restrict__ C2, int ldc,
                                          int K, int bm0, int bn0) {
    constexpr int WM = BM / 2, WN = BN / 2, MR = WM / 32, NR = WN / 32;
    __shared__ __align__(16) short As[BM * 64];
    __shared__ __align__(16) short Bs[BN * 64];
    const short* Ap = (const short*)A_;
    const short* Bp = (const short*)Bt_;

    int tid = threadIdx.x;
    int wid = tid >> 6, lane = tid & 63;
    int la = lane & 31, lk = lane >> 5;     // frag row/col, k-half
    int wr = wid >> 1, wc = wid & 1;
    int sa = la & 7;                         // read-side swizzle key (row&7)

    f32x16 acc[MR][NR];
#pragma unroll
    for (int m = 0; m < MR; ++m)
#pragma unroll
        for (int n = 0; n < NR; ++n)
#pragma unroll
            for (int i = 0; i < 16; ++i) acc[m][n][i] = 0.f;

    for (int k0 = 0; k0 < K; k0 += 64) {
        __syncthreads();
        // stage with SOURCE-side swizzle (LDS dest stays linear: rule #21)
#pragma unroll
        for (int i = 0; i < BM / 32; ++i) {
            int slot = i * 256 + tid;
            int row = slot >> 3, cs = (slot & 7) ^ (row & 7);
            gload16(Ap + (size_t)(bm0 + row) * lda + (k0 + cs * 8),
                    As + (i * 256 + wid * 64) * 8);
        }
#pragma unroll
        for (int i = 0; i < BN / 32; ++i) {
            int slot = i * 256 + tid;
            int row = slot >> 3, cs = (slot & 7) ^ (row & 7);
            gload16(Bp + (size_t)(bn0 + row) * ldb + (k0 + cs * 8),
                    Bs + (i * 256 + wid * 64) * 8);
        }
        asm volatile("s_waitcnt vmcnt(0)" ::: "memory");
        __syncthreads();

        // fragments: row r = ...+la, k-chunk kc = kk*2+lk, read at [r][ (kc^(r&7))*8 ]
        s16x8 af[MR][4], bfv[NR][4];
#pragma unroll
        for (int m = 0; m < MR; ++m)
#pragma unroll
            for (int kk = 0; kk < 4; ++kk)
                af[m][kk] = *(const s16x8*)&As[(wr * WM + m * 32 + la) * 64 +
                                               (((kk * 2 + lk) ^ sa) * 8)];
#pragma unroll
        for (int n = 0; n < NR; ++n)
#pragma unroll
            for (int kk = 0; kk < 4; ++kk)
                bfv[n][kk] = *(const s16x8*)&Bs[(wc * WN + n * 32 + la) * 64 +
                                                (((kk * 2 + lk) ^ sa) * 8)];
#pragma unroll
        for (int m = 0; m < MR; ++m)
#pragma unroll
            for (int n = 0; n < NR; ++n)
#pragma unroll
                for (int kk = 0; kk < 4; ++kk)
                    acc[m][n] = __builtin_amdgcn_mfma_f32_32x32x16_bf16(af[m][kk], bfv[n][kk],
                                                                        acc[m][n], 0, 0, 0);
    }

    // epilogue: 32x32 C/D layout col=lane&31, row=(i&3)+8*(i>>2)+4*(lane>>5)  [verified m74/m101]
#pragma unroll
    for (int m = 0; m < MR; ++m)
#pragma unroll
        for (int n = 0; n < NR; ++n)
#pragma unroll
            for (int i = 0; i < 16; ++i) {
                int gm = bm0 + wr * WM + m * 32 + (i & 3) + 8 * (i >> 2) + 4 * lk;
                int gn = bn0 + wc * WN + n * 32 + la;
                float v = acc[m][n][i];
                if constexpr (EPI == EPI_QKV) {
                    if (gn < 1024) {
                        ((bf16*)C0)[(size_t)gm * C_ + gn] = __float2bfloat16(v + bias[gn]);
                    } else if (gn < 2048) {
                        ((bf16*)C1)[(size_t)gm * C_ + (gn - 1024)] =
                            __float2bfloat16(v + bias2[gn - 1024]);
                    } else {
                        int d = gn - 2048, bb = gm >> 10, tt = gm & 1023;
                        ((bf16*)C2)[((size_t)(bb * 1024 + d)) * T_ + tt] =
                            __float2bfloat16(v + bias3[d]);
                    }
                } else if constexpr (EPI == EPI_RESID) {
                    float* cp = (float*)C0 + (size_t)gm * ldc + gn;
                    *cp = *cp + v + bias[gn];
                } else if constexpr (EPI == EPI_GELU) {
                    float xg = v + bias[gn];
                    float g = 0.5f * xg * (1.0f + erff(xg * 0.70710678118654752f));
                    ((bf16*)C0)[(size_t)gm * ldc + gn] = __float2bfloat16(g);
                } else if constexpr (EPI == EPI_PARTIAL) {
                    ((float*)C0)[(size_t)gm * ldc + gn] = v;
                }
            }
}

template<int BM, int BN, int EPI>
__global__ __launch_bounds__(256) void gemm_k(const bf16* A, int lda, const bf16* Bt, int ldb,
                                              const float* bias, void* C0, int ldc, int K) {
    gemm_tile<BM, BN, EPI>(A, lda, Bt, ldb, bias, nullptr, nullptr, C0, nullptr, nullptr, ldc, K,
                           blockIdx.y * BM, blockIdx.x * BN);
}

__global__ __launch_bounds__(256) void gemm_qkv_k(const bf16* a, const bf16* wt,
                                                  const float* bq, const float* bk, const float* bv,
                                                  bf16* qb, bf16* kb, bf16* vT) {
    gemm_tile<128, 128, EPI_QKV>(a, C_, wt, C_, bq, bk, bv, qb, kb, vT, 0, C_,
                                 blockIdx.y * 128, blockIdx.x * 128);
}

// split-K over blockIdx.z (4 slices of FF/4)
__global__ __launch_bounds__(256) void gemm_splitk_k(const bf16* A, int lda, const bf16* Bt, int ldb,
                                                     float* part, int Ksl) {
    int z = blockIdx.z;
    gemm_tile<128, 128, EPI_PARTIAL>(A + (size_t)z * Ksl, lda, Bt + (size_t)z * Ksl, ldb,
                                     nullptr, nullptr, nullptr,
                                     part + (size_t)z * M_ * C_, nullptr, nullptr, C_, Ksl,
                                     blockIdx.y * 128, blockIdx.x * 128);
}

// ---- split-K combine (+bias +residual into h), optionally fused next-layer LN1 -> a ----
template<int NPART, bool LN>
__global__ __launch_bounds__(256) void combine_ln_k(float* __restrict__ h,
                                                    const float* __restrict__ part,
                                                    const float* __restrict__ bias,
                                                    const float* __restrict__ lw,
                                                    const float* __restrict__ lb,
                                                    bf16* __restrict__ aout) {
    int row = blockIdx.x, t = threadIdx.x;
    float4 hv = ((const float4*)(h + (size_t)row * C_))[t];
    float4 bb = ((const float4*)bias)[t];
    hv.x += bb.x; hv.y += bb.y; hv.z += bb.z; hv.w += bb.w;
#pragma unroll
    for (int z = 0; z < NPART; ++z) {
        float4 p = ((const float4*)(part + (size_t)z * M_ * C_ + (size_t)row * C_))[t];
        hv.x += p.x; hv.y += p.y; hv.z += p.z; hv.w += p.w;
    }
    ((float4*)(h + (size_t)row * C_))[t] = hv;

    if constexpr (LN) {
        float s = hv.x + hv.y + hv.z + hv.w;
#pragma unroll
        for (int o = 32; o >= 1; o >>= 1) s += __shfl_xor(s, o);
        __shared__ float red[4];
        int wid = t >> 6, lane = t & 63;
        if (lane == 0) red[wid] = s;
        __syncthreads();
        float mean = (red[0] + red[1] + red[2] + red[3]) * (1.0f / C_);
        __syncthreads();
        float dx = hv.x - mean, dy = hv.y - mean, dz = hv.z - mean, dw = hv.w - mean;
        float ss = dx * dx + dy * dy + dz * dz + dw * dw;
#pragma unroll
        for (int o = 32; o >= 1; o >>= 1) ss += __shfl_xor(ss, o);
        if (lane == 0) red[wid] = ss;
        __syncthreads();
        float var = (red[0] + red[1] + red[2] + red[3]) * (1.0f / C_);
        float rs = rsqrtf(var + 1e-5f);
        float4 wv = ((const float4*)lw)[t];
        float4 bv = ((const float4*)lb)[t];
        bf16* ar = aout + (size_t)row * C_;
        ar[t * 4 + 0] = __float2bfloat16(dx * rs * wv.x + bv.x);
        ar[t * 4 + 1] = __float2bfloat16(dy * rs * wv.y + bv.y);
        ar[t * 4 + 2] = __float2bfloat16(dz * rs * wv.z + bv.z);
        ar[t * 4 + 3] = __float2bfloat16(dw * rs * wv.w + bv.w);
    }
}

// ---------------- Flash attention: one block per (64-q tile, head pair) ----------------
// 4 waves x 16 q-cols. S^T = mfma(K,Q); P redistributed in-register; O^T = mfma(V^T, P).
// KV tile 64, double-buffered LDS (stage t+1 before computing t), swizzled gload/ds_read.
__global__ __launch_bounds__(256) void flash_k(const bf16* __restrict__ qb,
                                               const bf16* __restrict__ kb,
                                               const bf16* __restrict__ vT,
                                               bf16* __restrict__ yb) {
    int qt = blockIdx.x, pair = blockIdx.y;
    int bb = pair >> 4, hh = pair & 15;
    __shared__ __align__(16) short Ks[2][64 * 64];
    __shared__ __align__(16) short Vs[2][64 * 64];

    int tid = threadIdx.x, wid = tid >> 6, lane = tid & 63, lr = lane & 15, lg = lane >> 4;
    int qrow = qt * 64 + wid * 16 + lr;

    const short* qp = (const short*)qb + ((size_t)(bb * T_ + qrow)) * C_ + hh * 64;
    s16x8 qf[2];
    qf[0] = *(const s16x8*)(qp + lg * 8);
    qf[1] = *(const s16x8*)(qp + 32 + lg * 8);

    const short* kbase = (const short*)kb + ((size_t)bb * T_) * C_ + hh * 64;  // row kv, stride C_
    const short* vbase = (const short*)vT + ((size_t)pair * 64) * T_;          // row d, stride T_

    auto stage = [&](int bf, int t) {
        int kv0 = t * 64;
#pragma unroll
        for (int i = 0; i < 2; ++i) {
            int slot = i * 256 + tid;
            int row = slot >> 3, cs = (slot & 7) ^ (row & 7);
            gload16(kbase + (size_t)(kv0 + row) * C_ + cs * 8, &Ks[bf][(i * 256 + wid * 64) * 8]);
        }
#pragma unroll
        for (int i = 0; i < 2; ++i) {
            int slot = i * 256 + tid;
            int row = slot >> 3, cs = (slot & 7) ^ (row & 7);
            gload16(vbase + (size_t)row * T_ + kv0 + cs * 8, &Vs[bf][(i * 256 + wid * 64) * 8]);
        }
    };

    f32x4 oacc[4];
    const f32x4 z4 = {0.f, 0.f, 0.f, 0.f};
#pragma unroll
    for (int m = 0; m < 4; ++m) oacc[m] = z4;
    float mrun = -INFINITY, lrun = 0.f;

    int srcl[4];
#pragma unroll
    for (int r = 0; r < 4; ++r) srcl[r] = ((((lg << 3) + 2 * r) & 15) >> 2) * 16 + lr;
    bool hihalf = lg >= 2;
    int swz = lr & 7;

    stage(0, 0);
    asm volatile("s_waitcnt vmcnt(0)" ::: "memory");
    __syncthreads();
    int cur = 0;

    for (int t = 0; t <= qt; ++t) {
        int kv0 = t * 64;
        if (t < qt) stage(cur ^ 1, t + 1);  // prefetch next tile into the other buffer

        f32x4 sacc[4];
#pragma unroll
        for (int m = 0; m < 4; ++m) sacc[m] = z4;
#pragma unroll
        for (int ks = 0; ks < 2; ++ks)
#pragma unroll
            for (int mr = 0; mr < 4; ++mr) {
                s16x8 kf = *(const s16x8*)&Ks[cur][(mr * 16 + lr) * 64 + (((ks * 4 + lg) ^ swz) * 8)];
                sacc[mr] = __builtin_amdgcn_mfma_f32_16x16x32_bf16(kf, qf[ks], sacc[mr], 0, 0, 0);
            }

        float p[4][4];
        bool diag = (t == qt);
#pragma unroll
        for (int mr = 0; mr < 4; ++mr)
#pragma unroll
            for (int i = 0; i < 4; ++i) {
                float s = sacc[mr][i] * 0.125f;
                if (diag && (kv0 + mr * 16 + lg * 4 + i) > qrow) s = -1e30f;
                p[mr][i] = s;
            }

        float tmax = p[0][0];
#pragma unroll
        for (int mr = 0; mr < 4; ++mr)
#pragma unroll
            for (int i = 0; i < 4; ++i) tmax = fmaxf(tmax, p[mr][i]);
        tmax = fmaxf(tmax, __shfl_xor(tmax, 16));
        tmax = fmaxf(tmax, __shfl_xor(tmax, 32));

        float mnew = fmaxf(mrun, tmax);
        float corr = __expf(mrun - mnew);
        float tsum = 0.f;
#pragma unroll
        for (int mr = 0; mr < 4; ++mr)
#pragma unroll
            for (int i = 0; i < 4; ++i) {
                p[mr][i] = __expf(p[mr][i] - mnew);
                tsum += p[mr][i];
            }
        tsum += __shfl_xor(tsum, 16);
        tsum += __shfl_xor(tsum, 32);
        lrun = lrun * corr + tsum;
        mrun = mnew;
#pragma unroll
        for (int m = 0; m < 4; ++m)
#pragma unroll
            for (int i = 0; i < 4; ++i) oacc[m][i] *= corr;

        unsigned pk[4][2];
#pragma unroll
        for (int mr = 0; mr < 4; ++mr) {
            pk[mr][0] = packbf(p[mr][0], p[mr][1]);
            pk[mr][1] = packbf(p[mr][2], p[mr][3]);
        }

#pragma unroll
        for (int b2 = 0; b2 < 2; ++b2) {
            union { unsigned u[4]; s16x8 v; } pf;
#pragma unroll
            for (int r = 0; r < 4; ++r) {
                unsigned t0 = (unsigned)__shfl((int)pk[2 * b2][r & 1], srcl[r], 64);
                unsigned t1 = (unsigned)__shfl((int)pk[2 * b2 + 1][r & 1], srcl[r], 64);
                pf.u[r] = hihalf ? t1 : t0;
            }
#pragma unroll
            for (int mr = 0; mr < 4; ++mr) {
                s16x8 av = *(const s16x8*)&Vs[cur][(mr * 16 + lr) * 64 + (((b2 * 4 + lg) ^ swz) * 8)];
                oacc[mr] = __builtin_amdgcn_mfma_f32_16x16x32_bf16(av, pf.v, oacc[mr], 0, 0, 0);
            }
        }

        asm volatile("s_waitcnt vmcnt(0)" ::: "memory");  // drain this iter's prefetch
        __syncthreads();
        cur ^= 1;
    }

    float linv = 1.0f / lrun;
    bf16* yrow = yb + ((size_t)(bb * T_ + qrow)) * C_ + hh * 64;
#pragma unroll
    for (int mr = 0; mr < 4; ++mr) {
        union { unsigned short us[4]; unsigned long long u64; } w;
#pragma unroll
        for (int i = 0; i < 4; ++i)
            w.us[i] = __builtin_bit_cast(unsigned short, __float2bfloat16(oacc[mr][i] * linv));
        *(unsigned long long*)(yrow + mr * 16 + lg * 4) = w.u64;
    }
}

extern "C" void kernel_launch(void* const* d_in, const int* in_sizes, int n_in,
                              void* d_out, int out_size, void* d_ws, size_t ws_size,
                              hipStream_t stream) {
    const float* x     = (const float*)d_in[0];
    const float* Wq    = (const float*)d_in[1];
    const float* Wk    = (const float*)d_in[2];
    const float* Wv    = (const float*)d_in[3];
    const float* Wp    = (const float*)d_in[4];
    const float* bq    = (const float*)d_in[5];
    const float* bk    = (const float*)d_in[6];
    const float* bv    = (const float*)d_in[7];
    const float* bp    = (const float*)d_in[8];
    const float* ln1w  = (const float*)d_in[9];
    const float* ln1b  = (const float*)d_in[10];
    const float* ln2w  = (const float*)d_in[11];
    const float* ln2b  = (const float*)d_in[12];
    const float* W1    = (const float*)d_in[13];
    const float* b1    = (const float*)d_in[14];
    const float* W2    = (const float*)d_in[15];
    const float* b2    = (const float*)d_in[16];
    const float* lnfw  = (const float*)d_in[17];
    const float* lnfb  = (const float*)d_in[18];

    float* h = (float*)d_out;  // residual stream lives in d_out (fp32 [M,C])
    hipMemcpyAsync(h, x, (size_t)M_ * C_ * 4, hipMemcpyDeviceToDevice, stream);

    // ---- workspace carve ----
    char* base = (char*)d_ws;
    size_t off = 0;
    auto carve = [&](size_t bytes) {
        char* r = base + off;
        off += (bytes + 255) & ~(size_t)255;
        return r;
    };
    bf16*  a    = (bf16*)carve((size_t)M_ * C_ * 2);
    bf16*  qb   = (bf16*)carve((size_t)M_ * C_ * 2);
    bf16*  kb   = (bf16*)carve((size_t)M_ * C_ * 2);
    bf16*  vT   = (bf16*)carve((size_t)M_ * C_ * 2);      // [B*H*64, T]
    bf16*  yb   = (bf16*)carve((size_t)M_ * C_ * 2);
    bf16*  hid  = (bf16*)carve((size_t)M_ * FF * 2);
    float* part = (float*)carve((size_t)4 * M_ * C_ * 4); // split-K partials (32MB)

    // weight slab: all 8 layers pre-transposed if ws allows, else per-layer
    bool PRE = (off + (size_t)L_ * WSLAB * 2 + 4096) <= ws_size;
    bf16* wt = (bf16*)carve((size_t)(PRE ? L_ : 1) * WSLAB * 2);

    dim3 tb(256);
    dim3 tpb(32, 8);

    if (PRE)
        transpose_all_k<<<dim3(12288, 1, L_), tpb, 0, stream>>>(Wq, Wk, Wv, Wp, W1, W2, wt, 0);

    // LN1 for layer 0 (later layers get it fused into combine_ln_k)
    ln_kernel<bf16><<<M_, tb, 0, stream>>>(h, ln1w, ln1b, a);

    for (int l = 0; l < L_; ++l) {
        if (!PRE)
            transpose_all_k<<<dim3(12288, 1, 1), tpb, 0, stream>>>(Wq, Wk, Wv, Wp, W1, W2, wt, l);
        bf16* wl = wt + (size_t)(PRE ? l : 0) * WSLAB;

        // QKV fused GEMM
        gemm_qkv_k<<<dim3(24, 16), tb, 0, stream>>>(a, wl, bq + l * C_, bk + l * C_, bv + l * C_,
                                                    qb, kb, vT);

        // flash attention
        flash_k<<<dim3(16, 32), tb, 0, stream>>>(qb, kb, vT, yb);

        // out proj + residual into h
        gemm_k<64, 128, EPI_RESID><<<dim3(8, 32), tb, 0, stream>>>(yb, C_, wl + (size_t)3 * 1048576,
                                                                   C_, bp + l * C_, h, C_, C_);

        // LN2 -> a
        ln_kernel<bf16><<<M_, tb, 0, stream>>>(h, ln2w + l * C_, ln2b + l * C_, a);

        // MLP up + GELU -> hid
        gemm_k<128, 128, EPI_GELU><<<dim3(FF / 128, M_ / 128), tb, 0, stream>>>(
            a, C_, wl + (size_t)4 * 1048576, C_, b1 + l * FF, hid, FF, C_);

        // MLP down: split-K=4 partials, then combine (+bias +residual [+next LN1])
        gemm_splitk_k<<<dim3(8, 16, 4), tb, 0, stream>>>(hid, FF, wl + (size_t)8 * 1048576, FF,
                                                         part, FF / 4);
        if (l < L_ - 1)
            combine_ln_k<4, true><<<M_, tb, 0, stream>>>(h, part, b2 + l * C_,
                                                         ln1w + (l + 1) * C_, ln1b + (l + 1) * C_, a);
        else
            combine_ln_k<4, false><<<M_, tb, 0, stream>>>(h, part, b2 + l * C_,
                                                          nullptr, nullptr, nullptr);
    }

    // final LN in place (fp32 out)
    ln_kernel<float><<<M_, tb, 0, stream>>>(h, lnfw, lnfb, h);
}